// Round 15
// baseline (95.223 us; speedup 1.0000x reference)
//
#include <hip/hip_runtime.h>

#define B_   4
#define S_   1024
#define D_   768
#define H_   12
#define HD_  64
#define NROW (B_*S_)          // 4096
#define RSTRIDE (H_*HD_)      // 768
#define NBH  (B_*H_)          // 48
#define LOG2E 1.44269504f

typedef __bf16 bf16_t;
typedef bf16_t bf16x8 __attribute__((ext_vector_type(8)));
typedef float  f32x4  __attribute__((ext_vector_type(4)));
typedef float  f32x16 __attribute__((ext_vector_type(16)));
typedef unsigned int u32x4 __attribute__((ext_vector_type(4)));

__device__ __forceinline__ unsigned short bf16b(float f){
  bf16_t b = (bf16_t)f;
  return __builtin_bit_cast(unsigned short, b);
}
__device__ __forceinline__ float bf2f(unsigned short u){
  return (float)__builtin_bit_cast(bf16_t, u);
}

__device__ __forceinline__ void gload16(const void* g, void* l){
  __builtin_amdgcn_global_load_lds(
      (const __attribute__((address_space(1))) void*)g,
      (__attribute__((address_space(3))) void*)l, 16, 0, 0);
}

__device__ __forceinline__ unsigned int cvtpk(float lo, float hi){
  unsigned int r;
  asm("v_cvt_pk_bf16_f32 %0, %1, %2" : "=v"(r) : "v"(lo), "v"(hi));
  return r;
}

__device__ __forceinline__ void plswap(unsigned int &a, unsigned int &b){
  asm volatile("v_permlane32_swap_b32 %0, %1" : "+v"(a), "+v"(b));
}

// ---------------- fused prep: RMSNorm(q) + all f32->bf16 casts, one launch ----------------
__global__ void prep_kernel(const float* __restrict__ q, const float* __restrict__ w_norm,
                            bf16_t* __restrict__ qn,
                            const float* __restrict__ wq,  bf16_t* __restrict__ wqb,
                            const float* __restrict__ wkv, bf16_t* __restrict__ wkvb,
                            const float* __restrict__ wo,  bf16_t* __restrict__ wob,
                            const float* __restrict__ kv,  bf16_t* __restrict__ kvb){
  int bid = blockIdx.x;
  if (bid < NROW){
    int row = bid;
    const float* src = q + (size_t)row*D_;
    float vals[3]; float ss = 0.f;
#pragma unroll
    for (int i=0;i<3;i++){ float v = src[threadIdx.x + i*256]; vals[i]=v; ss += v*v; }
#pragma unroll
    for (int m=1;m<64;m<<=1) ss += __shfl_xor(ss, m, 64);
    __shared__ float red[4];
    if ((threadIdx.x & 63) == 0) red[threadIdx.x>>6] = ss;
    __syncthreads();
    float tot = red[0]+red[1]+red[2]+red[3];
    float rs = rsqrtf(tot*(1.0f/D_) + 1e-5f);
#pragma unroll
    for (int i=0;i<3;i++){
      int c = threadIdx.x + i*256;
      qn[(size_t)row*D_ + c] = (bf16_t)(vals[i]*rs*w_norm[c]);
    }
  } else {
    int i = (bid - NROW)*256 + threadIdx.x;
    const int n0 = D_*D_/4, n1 = 2*D_*D_/4, n2 = D_*D_/4, n3 = NROW*D_/4;
    const float* s; bf16_t* d; int off;
    if (i < n0){ s = wq; d = wqb; off = i; }
    else if (i < n0+n1){ s = wkv; d = wkvb; off = i - n0; }
    else if (i < n0+n1+n2){ s = wo; d = wob; off = i - n0 - n1; }
    else if (i < n0+n1+n2+n3){ s = kv; d = kvb; off = i - n0 - n1 - n2; }
    else return;
    float4 v = reinterpret_cast<const float4*>(s)[off];
    ushort4 o;
    o.x = bf16b(v.x); o.y = bf16b(v.y); o.z = bf16b(v.z); o.w = bf16b(v.w);
    reinterpret_cast<ushort4*>(d)[off] = o;
  }
}

// ---------------- RoPE + pack into MFMA-fragment-major layout (bf16 src) ----------------
// dstfrag[((bh*32 + tile)*4 + c)*512 + hi*256 + lq*8 + j] = X[b,s=tile*32+lq][h, d=c*16+hi*8+j]
__device__ __forceinline__ void rope_body(const bf16_t* __restrict__ src, const int* __restrict__ pos,
                                          const float* __restrict__ freqs, bf16_t* __restrict__ dstfrag,
                                          int srcStride, float outScale, int idx){
  int row = idx / (H_*32);        // b*1024 + s
  int rem = idx % (H_*32);
  int h = rem >> 5, f = rem & 31;
  float p0 = (float)pos[row*2+0], p1 = (float)pos[row*2+1];
  float ang = p0*freqs[h*32+f] + p1*freqs[H_*32 + h*32 + f];
  float s, c;
  __sincosf(ang, &s, &c);
  ushort2 xx = *reinterpret_cast<const ushort2*>(src + (size_t)row*srcStride + h*HD_ + 2*f);
  float xr = bf2f(xx.x), xi = bf2f(xx.y);
  float orr = (xr*c - xi*s)*outScale;
  float oi  = (xr*s + xi*c)*outScale;
  int bh   = (row >> 10)*H_ + h;
  int tile = (row & 1023) >> 5;
  int lq   = row & 31;
  int cc = f >> 3, hi = (f >> 2) & 1, j = (f & 3)*2;
  bf16_t* dst = dstfrag + (((size_t)(bh*32 + tile)*4 + cc)*512 + hi*256 + lq*8 + j);
  ushort2 o; o.x = bf16b(orr); o.y = bf16b(oi);
  *reinterpret_cast<ushort2*>(dst) = o;
}

// ---------------- fused pack: rope(q) + rope(k) + V fragment pack (bf16 src) ----------------
// vfrag[(bh*32+kb)*2048 + dt*1024 + ks*512 + hi*256 + lq*8 + j]
//   = V[b, key=kb*32+ks*16+hi*8+j][h, d=dt*32+lq]
__global__ void pack_kernel(const bf16_t* __restrict__ qp, const int* __restrict__ posq,
                            const bf16_t* __restrict__ kvp, const int* __restrict__ posk,
                            const float* __restrict__ freqs,
                            bf16_t* __restrict__ qh, bf16_t* __restrict__ kh,
                            bf16_t* __restrict__ vfrag){
  const int RB = (NROW*H_*32)/256;   // 6144
  int bid = blockIdx.x;
  if (bid < RB){
    rope_body(qp, posq, freqs, qh, D_, 0.125f*LOG2E, bid*256 + threadIdx.x);
  } else if (bid < 2*RB){
    rope_body(kvp, posk, freqs, kh, 2*D_, 1.0f, (bid-RB)*256 + threadIdx.x);
  } else {
    int idx = bid - 2*RB;            // 0..1535
    int kb = idx & 31, bh = idx >> 5;
    int b = bh / H_, h = bh % H_;
    int t = threadIdx.x;
    int lq = t & 31, hi = (t >> 5) & 1, ks = (t >> 6) & 1, dt = t >> 7;
    const bf16_t* src = kvp + ((size_t)(b*S_ + kb*32 + ks*16 + hi*8))*(2*D_) + D_ + h*HD_ + dt*32 + lq;
    bf16_t tmp[8];
#pragma unroll
    for (int j=0;j<8;j++) tmp[j] = src[(size_t)j*(2*D_)];
    *reinterpret_cast<bf16x8*>(vfrag + (size_t)(bh*32 + kb)*2048 + t*8) =
        *reinterpret_cast<bf16x8*>(tmp);
  }
}

// ---------------- bf16 GEMM body: C[M,N] = A[M,K] * W[N,K]^T + bias ----------------
template<typename OutT>
__device__ __forceinline__ void gemm_body(const bf16_t* __restrict__ A, const bf16_t* __restrict__ W,
                                          const float* __restrict__ bias, OutT* __restrict__ C,
                                          int N, int K, int row0, int col0,
                                          bf16_t* As, bf16_t* Bs){
  const int tid  = threadIdx.x;
  const int lane = tid & 63;
  const int wv   = tid >> 6;
  const int wr = wv >> 1, wc = wv & 1;
  const int l4 = lane >> 4, lm = lane & 15;

  f32x4 acc[4][4] = {};

  for (int kt = 0; kt < K; kt += 32){
#pragma unroll
    for (int i=0;i<2;i++){
      int c = i*256 + tid;
      int r = c >> 2, kc = c & 3;
      gload16(A + (size_t)(row0+r)*K + kt + kc*8, As + (size_t)(i*256 + wv*64)*8);
    }
#pragma unroll
    for (int i=0;i<2;i++){
      int c = i*256 + tid;
      int r = c >> 2, kc = c & 3;
      gload16(W + (size_t)(col0+r)*K + kt + kc*8, Bs + (size_t)(i*256 + wv*64)*8);
    }
    __syncthreads();

    bf16x8 af[4], bfr[4];
#pragma unroll
    for (int mi=0;mi<4;mi++)
      af[mi] = *reinterpret_cast<const bf16x8*>(As + (wr*64 + mi*16 + lm)*32 + l4*8);
#pragma unroll
    for (int ni=0;ni<4;ni++)
      bfr[ni] = *reinterpret_cast<const bf16x8*>(Bs + (wc*64 + ni*16 + lm)*32 + l4*8);
#pragma unroll
    for (int mi=0;mi<4;mi++)
#pragma unroll
      for (int ni=0;ni<4;ni++)
        acc[mi][ni] = __builtin_amdgcn_mfma_f32_16x16x32_bf16(af[mi], bfr[ni], acc[mi][ni], 0,0,0);
    __syncthreads();
  }

#pragma unroll
  for (int mi=0;mi<4;mi++){
#pragma unroll
    for (int ni=0;ni<4;ni++){
      int col = col0 + wc*64 + ni*16 + lm;
      float bv = bias[col];
#pragma unroll
      for (int j=0;j<4;j++){
        int row = row0 + wr*64 + mi*16 + l4*4 + j;
        C[(size_t)row*N + col] = (OutT)(acc[mi][ni][j] + bv);
      }
    }
  }
}

__global__ void gemm_kernel(const bf16_t* __restrict__ A, const bf16_t* __restrict__ W,
                            const float* __restrict__ bias, float* __restrict__ C,
                            int N, int K){
  __shared__ bf16_t As[128*32];
  __shared__ bf16_t Bs[128*32];
  gemm_body<float>(A, W, bias, C, N, K, blockIdx.x*128, blockIdx.y*128, As, Bs);
}

// fused q-proj + kv-proj: 576 blocks, XCD-bijective remap; bf16 outputs
__global__ void gemm_qkv_kernel(const bf16_t* __restrict__ qn, const bf16_t* __restrict__ kvb,
                                const bf16_t* __restrict__ wq, const bf16_t* __restrict__ wkv,
                                const float* __restrict__ bq, const float* __restrict__ bkv,
                                bf16_t* __restrict__ qp, bf16_t* __restrict__ kvp){
  __shared__ bf16_t As[128*32];
  __shared__ bf16_t Bs[128*32];
  int l = (blockIdx.x & 7)*72 + (blockIdx.x >> 3);  // 576 = 8*72
  int x = l & 31, y = l >> 5;
  if (y < 6)
    gemm_body<bf16_t>(qn,  wq,  bq,  qp,  D_,   D_, x*128, y*128,     As, Bs);
  else
    gemm_body<bf16_t>(kvb, wkv, bkv, kvp, 2*D_, D_, x*128, (y-6)*128, As, Bs);
}

// ---------------- one attention step: QK^T -> exp2 -> P repack -> PV ----------------
// psum4: 4 interleaved partial sums (serial f32 add chain 16 -> 4; no fast-math
// reassociation happens otherwise, costing ~64 cyc/iter of pure dependency).
__device__ __forceinline__ void attn_step(const bf16x8 (&kf)[4], const bf16x8 (&vf)[4],
                                          const bf16x8 (&qf)[4], f32x16 (&acc_o)[2],
                                          float (&psum4)[4]){
  f32x16 accs = {};
#pragma unroll
  for (int c=0;c<4;c++)
    accs = __builtin_amdgcn_mfma_f32_32x32x16_bf16(kf[c], qf[c], accs, 0,0,0);
#pragma unroll
  for (int r=0;r<16;r++){
    float v = exp2f(accs[r]);
    accs[r] = v;
    psum4[r&3] += v;
  }
  bf16x8 pa[2];
#pragma unroll
  for (int ks=0;ks<2;ks++){
    const int base = ks*8;
    unsigned int a0 = cvtpk(accs[base+0], accs[base+1]);
    unsigned int a1 = cvtpk(accs[base+2], accs[base+3]);
    unsigned int b0 = cvtpk(accs[base+4], accs[base+5]);
    unsigned int b1 = cvtpk(accs[base+6], accs[base+7]);
    plswap(a0, b0);
    plswap(a1, b1);
    u32x4 w; w[0]=a0; w[1]=a1; w[2]=b0; w[3]=b1;
    pa[ks] = __builtin_bit_cast(bf16x8, w);
  }
#pragma unroll
  for (int dt=0;dt<2;dt++)
#pragma unroll
    for (int ks=0;ks<2;ks++)
      acc_o[dt] = __builtin_amdgcn_mfma_f32_32x32x16_bf16(pa[ks], vf[dt*2+ks], acc_o[dt], 0,0,0);
}

// ---------------- flash attention: fragment streaming, occupancy-first ----------------
// R14 base, but: NO register double-buffers (K/V loaded per-iteration; compiler
// hoists within budget) -> ~118 live VGPRs -> launch_bounds(256,4) = 4 waves/SIMD
// (vs 3 with prefetch). R14 showed prefetch arrangement is not the limiter; the
// kernel is latency-bound, so resident-wave count is the lever. psum in 4 partials.
// 1536 blocks x 256 thr (4 waves). Each wave one key-quarter (8 iters, no barriers).
// Partials merged through LDS in f32; all 4 waves split the merge.
__global__ __launch_bounds__(256, 4)
void attn_kernel(const bf16_t* __restrict__ Qf, const bf16_t* __restrict__ Kf,
                 const bf16_t* __restrict__ Vf, bf16_t* __restrict__ Oh){
  const int lane = threadIdx.x & 63;
  const int wv   = threadIdx.x >> 6;  // key-quarter 0..3
  const int hi = lane >> 5, lq = lane & 31;
  // XCD-chunked bijective remap: 1536 = 8*192 (6 heads per XCD)
  int l = ((int)blockIdx.x & 7)*192 + ((int)blockIdx.x >> 3);
  const int bh = l >> 5;              // 0..47
  const int qt = l & 31;              // 0..31
  const int q0 = qt*32;
  const int b = bh / H_, h = bh % H_;
  const size_t headoff = ((size_t)b*S_*H_ + h)*HD_;

  __shared__ float part[4][64][33];   // f32 partials, padded (conflict-free)
  __shared__ float ps[4][32];

  // Q fragments (B-operand): coalesced; same q-tile for all 4 waves
  bf16x8 qf[4];
  {
    const bf16_t* qp_ = Qf + (size_t)(bh*32 + qt)*2048 + lane*8;
#pragma unroll
    for (int c=0;c<4;c++)
      qf[c] = *reinterpret_cast<const bf16x8*>(qp_ + c*512);
  }

  const bf16_t* kbase = Kf + ((size_t)bh*32 + wv*8)*2048 + lane*8;
  const bf16_t* vbase = Vf + ((size_t)bh*32 + wv*8)*2048 + lane*8;

  float psum4[4] = {0.f, 0.f, 0.f, 0.f};
  f32x16 acc_o[2] = {};   // [dt]

#pragma unroll
  for (int t=0; t<8; ++t){
    bf16x8 kf[4], vf[4];
    const bf16_t* kp = kbase + (size_t)t*2048;
    const bf16_t* vp = vbase + (size_t)t*2048;
#pragma unroll
    for (int c=0;c<4;c++){
      kf[c] = *reinterpret_cast<const bf16x8*>(kp + c*512);
      vf[c] = *reinterpret_cast<const bf16x8*>(vp + c*512);
    }
    attn_step(kf, vf, qf, acc_o, psum4);
  }

  // ---- in-block split-K merge (f32), all 4 waves participate ----
  float psum = (psum4[0] + psum4[1]) + (psum4[2] + psum4[3]);
  float tp = psum + __shfl_xor(psum, 32, 64);   // row lq's partial denom, this quarter
#pragma unroll
  for (int dt=0;dt<2;dt++)
#pragma unroll
    for (int r=0;r<16;r++)
      part[wv][lane][dt*16+r] = acc_o[dt][r];
  if (lane < 32) ps[wv][lq] = tp;
  __syncthreads();

  // each wave handles one (dt, r-half) slice of the 32 outputs
  const int dt = wv >> 1;
  const int rbase = (wv & 1)*8;
  float tot = ps[0][lq] + ps[1][lq] + ps[2][lq] + ps[3][lq];
  float inv = 1.0f / tot;

  bf16_t* obase = Oh + headoff;
#pragma unroll
  for (int ri=0;ri<8;ri++){
    int r = rbase + ri;
    float s = part[0][lane][dt*16+r] + part[1][lane][dt*16+r]
            + part[2][lane][dt*16+r] + part[3][lane][dt*16+r];
    // row s's denom lives on lane s (lq==s); C/D row for (r,hi) is crow = (r&3)+8*(r>>2)+4*hi
    float invr = __shfl(inv, (r&3) + 8*(r>>2) + 4*hi, 64);
    int qq = q0 + (r&3) + 8*(r>>2) + 4*hi;
    obase[(size_t)qq*RSTRIDE + dt*32 + lq] = (bf16_t)(s*invr);
  }
}

// ---------------- launch ----------------
extern "C" void kernel_launch(void* const* d_in, const int* in_sizes, int n_in,
                              void* d_out, int out_size, void* d_ws, size_t ws_size,
                              hipStream_t stream) {
  const float* q      = (const float*)d_in[0];
  const float* kv     = (const float*)d_in[1];
  const int*   posq   = (const int*)d_in[2];
  const int*   posk   = (const int*)d_in[3];
  const float* w_norm = (const float*)d_in[4];
  const float* w_q    = (const float*)d_in[5];
  const float* b_q    = (const float*)d_in[6];
  const float* w_kv   = (const float*)d_in[7];
  const float* b_kv   = (const float*)d_in[8];
  const float* w_out  = (const float*)d_in[9];
  const float* b_out  = (const float*)d_in[10];
  const float* freqs  = (const float*)d_in[11];
  float* out = (float*)d_out;

  char* p = (char*)d_ws;
  bf16_t* qn   = (bf16_t*)p; p += (size_t)NROW*D_*2;
  bf16_t* kvb  = (bf16_t*)p; p += (size_t)NROW*D_*2;
  bf16_t* wqb  = (bf16_t*)p; p += (size_t)D_*D_*2;
  bf16_t* wkvb = (bf16_t*)p; p += (size_t)2*D_*D_*2;
  bf16_t* wob  = (bf16_t*)p; p += (size_t)D_*D_*2;
  bf16_t* qh   = (bf16_t*)p; p += (size_t)NROW*D_*2;    // Q fragments
  bf16_t* kh   = (bf16_t*)p; p += (size_t)NROW*D_*2;    // K fragments
  bf16_t* vt   = (bf16_t*)p; p += (size_t)NBH*HD_*S_*2; // V fragments
  bf16_t* oh   = (bf16_t*)p; p += (size_t)NROW*D_*2;
  bf16_t* qp   = (bf16_t*)p; p += (size_t)NROW*D_*2;    // q-proj (bf16)
  bf16_t* kvp  = (bf16_t*)p; p += (size_t)NROW*2*D_*2;  // kv-proj (bf16)

  // 1) RMSNorm + all casts
  prep_kernel<<<NROW + 5376, 256, 0, stream>>>(q, w_norm, qn,
                                               w_q, wqb, w_kv, wkvb, w_out, wob, kv, kvb);
  // 2) q-proj + kv-proj (fused, XCD-remapped, bf16 out)
  gemm_qkv_kernel<<<576, 256, 0, stream>>>(qn, kvb, wqb, wkvb, b_q, b_kv, qp, kvp);
  // 3) RoPE(q)+RoPE(k)+V pack into fragment-major layout (bf16 in)
  //    q scale = 1/sqrt(64) * log2(e) so attention uses exp2 with no rescale
  pack_kernel<<<2*6144 + 1536, 256, 0, stream>>>(qp, posq, kvp, posk, freqs, qh, kh, vt);
  // 4) attention (occupancy-first: 4 waves/SIMD, no reg prefetch, split psum)
  attn_kernel<<<1536, 256, 0, stream>>>(qh, kh, vt, oh);
  // 5) output projection -> f32 d_out
  gemm_kernel<<<dim3(32, 6), 256, 0, stream>>>(oh, wob, b_out, out, D_, D_);
}

// Round 16
// 88.996 us; speedup vs baseline: 1.0700x; 1.0700x over previous
//
#include <hip/hip_runtime.h>

#define B_   4
#define S_   1024
#define D_   768
#define H_   12
#define HD_  64
#define NROW (B_*S_)          // 4096
#define RSTRIDE (H_*HD_)      // 768
#define NBH  (B_*H_)          // 48
#define LOG2E 1.44269504f

typedef __bf16 bf16_t;
typedef bf16_t bf16x8 __attribute__((ext_vector_type(8)));
typedef float  f32x4  __attribute__((ext_vector_type(4)));
typedef float  f32x16 __attribute__((ext_vector_type(16)));
typedef unsigned int u32x4 __attribute__((ext_vector_type(4)));

__device__ __forceinline__ unsigned short bf16b(float f){
  bf16_t b = (bf16_t)f;
  return __builtin_bit_cast(unsigned short, b);
}
__device__ __forceinline__ float bf2f(unsigned short u){
  return (float)__builtin_bit_cast(bf16_t, u);
}

__device__ __forceinline__ void gload16(const void* g, void* l){
  __builtin_amdgcn_global_load_lds(
      (const __attribute__((address_space(1))) void*)g,
      (__attribute__((address_space(3))) void*)l, 16, 0, 0);
}

__device__ __forceinline__ unsigned int cvtpk(float lo, float hi){
  unsigned int r;
  asm("v_cvt_pk_bf16_f32 %0, %1, %2" : "=v"(r) : "v"(lo), "v"(hi));
  return r;
}

__device__ __forceinline__ void plswap(unsigned int &a, unsigned int &b){
  asm volatile("v_permlane32_swap_b32 %0, %1" : "+v"(a), "+v"(b));
}

// ---------------- fused prep: RMSNorm(q) + all f32->bf16 casts, one launch ----------------
__global__ void prep_kernel(const float* __restrict__ q, const float* __restrict__ w_norm,
                            bf16_t* __restrict__ qn,
                            const float* __restrict__ wq,  bf16_t* __restrict__ wqb,
                            const float* __restrict__ wkv, bf16_t* __restrict__ wkvb,
                            const float* __restrict__ wo,  bf16_t* __restrict__ wob,
                            const float* __restrict__ kv,  bf16_t* __restrict__ kvb){
  int bid = blockIdx.x;
  if (bid < NROW){
    int row = bid;
    const float* src = q + (size_t)row*D_;
    float vals[3]; float ss = 0.f;
#pragma unroll
    for (int i=0;i<3;i++){ float v = src[threadIdx.x + i*256]; vals[i]=v; ss += v*v; }
#pragma unroll
    for (int m=1;m<64;m<<=1) ss += __shfl_xor(ss, m, 64);
    __shared__ float red[4];
    if ((threadIdx.x & 63) == 0) red[threadIdx.x>>6] = ss;
    __syncthreads();
    float tot = red[0]+red[1]+red[2]+red[3];
    float rs = rsqrtf(tot*(1.0f/D_) + 1e-5f);
#pragma unroll
    for (int i=0;i<3;i++){
      int c = threadIdx.x + i*256;
      qn[(size_t)row*D_ + c] = (bf16_t)(vals[i]*rs*w_norm[c]);
    }
  } else {
    int i = (bid - NROW)*256 + threadIdx.x;
    const int n0 = D_*D_/4, n1 = 2*D_*D_/4, n2 = D_*D_/4, n3 = NROW*D_/4;
    const float* s; bf16_t* d; int off;
    if (i < n0){ s = wq; d = wqb; off = i; }
    else if (i < n0+n1){ s = wkv; d = wkvb; off = i - n0; }
    else if (i < n0+n1+n2){ s = wo; d = wob; off = i - n0 - n1; }
    else if (i < n0+n1+n2+n3){ s = kv; d = kvb; off = i - n0 - n1 - n2; }
    else return;
    float4 v = reinterpret_cast<const float4*>(s)[off];
    ushort4 o;
    o.x = bf16b(v.x); o.y = bf16b(v.y); o.z = bf16b(v.z); o.w = bf16b(v.w);
    reinterpret_cast<ushort4*>(d)[off] = o;
  }
}

// ---------------- RoPE + pack into MFMA-fragment-major layout (bf16 src) ----------------
// dstfrag[((bh*32 + tile)*4 + c)*512 + hi*256 + lq*8 + j] = X[b,s=tile*32+lq][h, d=c*16+hi*8+j]
__device__ __forceinline__ void rope_body(const bf16_t* __restrict__ src, const int* __restrict__ pos,
                                          const float* __restrict__ freqs, bf16_t* __restrict__ dstfrag,
                                          int srcStride, float outScale, int idx){
  int row = idx / (H_*32);        // b*1024 + s
  int rem = idx % (H_*32);
  int h = rem >> 5, f = rem & 31;
  float p0 = (float)pos[row*2+0], p1 = (float)pos[row*2+1];
  float ang = p0*freqs[h*32+f] + p1*freqs[H_*32 + h*32 + f];
  float s, c;
  __sincosf(ang, &s, &c);
  ushort2 xx = *reinterpret_cast<const ushort2*>(src + (size_t)row*srcStride + h*HD_ + 2*f);
  float xr = bf2f(xx.x), xi = bf2f(xx.y);
  float orr = (xr*c - xi*s)*outScale;
  float oi  = (xr*s + xi*c)*outScale;
  int bh   = (row >> 10)*H_ + h;
  int tile = (row & 1023) >> 5;
  int lq   = row & 31;
  int cc = f >> 3, hi = (f >> 2) & 1, j = (f & 3)*2;
  bf16_t* dst = dstfrag + (((size_t)(bh*32 + tile)*4 + cc)*512 + hi*256 + lq*8 + j);
  ushort2 o; o.x = bf16b(orr); o.y = bf16b(oi);
  *reinterpret_cast<ushort2*>(dst) = o;
}

// ---------------- fused pack: rope(q) + rope(k) + V fragment pack (bf16 src) ----------------
// vfrag[(bh*32+kb)*2048 + dt*1024 + ks*512 + hi*256 + lq*8 + j]
//   = V[b, key=kb*32+ks*16+hi*8+j][h, d=dt*32+lq]
__global__ void pack_kernel(const bf16_t* __restrict__ qp, const int* __restrict__ posq,
                            const bf16_t* __restrict__ kvp, const int* __restrict__ posk,
                            const float* __restrict__ freqs,
                            bf16_t* __restrict__ qh, bf16_t* __restrict__ kh,
                            bf16_t* __restrict__ vfrag){
  const int RB = (NROW*H_*32)/256;   // 6144
  int bid = blockIdx.x;
  if (bid < RB){
    rope_body(qp, posq, freqs, qh, D_, 0.125f*LOG2E, bid*256 + threadIdx.x);
  } else if (bid < 2*RB){
    rope_body(kvp, posk, freqs, kh, 2*D_, 1.0f, (bid-RB)*256 + threadIdx.x);
  } else {
    int idx = bid - 2*RB;            // 0..1535
    int kb = idx & 31, bh = idx >> 5;
    int b = bh / H_, h = bh % H_;
    int t = threadIdx.x;
    int lq = t & 31, hi = (t >> 5) & 1, ks = (t >> 6) & 1, dt = t >> 7;
    const bf16_t* src = kvp + ((size_t)(b*S_ + kb*32 + ks*16 + hi*8))*(2*D_) + D_ + h*HD_ + dt*32 + lq;
    bf16_t tmp[8];
#pragma unroll
    for (int j=0;j<8;j++) tmp[j] = src[(size_t)j*(2*D_)];
    *reinterpret_cast<bf16x8*>(vfrag + (size_t)(bh*32 + kb)*2048 + t*8) =
        *reinterpret_cast<bf16x8*>(tmp);
  }
}

// ---------------- bf16 GEMM body, BK=64: C[M,N] = A[M,K] * W[N,K]^T + bias ----------------
// 128x128 tile, BK=64 (2 barriers per 32 MFMA/wave instead of per 16).
// LDS rows are 128B => XOR-swizzle the 16B slot by (row&7): pre-swizzled global
// source + same XOR on ds_read (rule: both-sides-or-neither with global_load_lds).
// Banks: (row*32 + slot^ (row&7) *4)%32 spreads 8 rows over 8 bank-quads -> 2 lanes/bank (free).
template<typename OutT>
__device__ __forceinline__ void gemm_body(const bf16_t* __restrict__ A, const bf16_t* __restrict__ W,
                                          const float* __restrict__ bias, OutT* __restrict__ C,
                                          int N, int K, int row0, int col0,
                                          bf16_t* As, bf16_t* Bs){
  const int tid  = threadIdx.x;
  const int lane = tid & 63;
  const int wv   = tid >> 6;
  const int wr = wv >> 1, wc = wv & 1;
  const int l4 = lane >> 4, lm = lane & 15;

  f32x4 acc[4][4] = {};

  for (int kt = 0; kt < K; kt += 64){
#pragma unroll
    for (int i=0;i<4;i++){
      int c = i*256 + tid;
      int r = c >> 3, kc = (c & 7) ^ (r & 7);
      gload16(A + (size_t)(row0+r)*K + kt + kc*8, As + (size_t)(i*256 + wv*64)*8);
    }
#pragma unroll
    for (int i=0;i<4;i++){
      int c = i*256 + tid;
      int r = c >> 3, kc = (c & 7) ^ (r & 7);
      gload16(W + (size_t)(col0+r)*K + kt + kc*8, Bs + (size_t)(i*256 + wv*64)*8);
    }
    __syncthreads();

#pragma unroll
    for (int kk=0; kk<2; kk++){
      bf16x8 af[4], bfr[4];
#pragma unroll
      for (int mi=0;mi<4;mi++){
        int r = wr*64 + mi*16 + lm;
        int s = (kk*4 + l4) ^ (r & 7);
        af[mi] = *reinterpret_cast<const bf16x8*>(As + r*64 + s*8);
      }
#pragma unroll
      for (int ni=0;ni<4;ni++){
        int r = wc*64 + ni*16 + lm;
        int s = (kk*4 + l4) ^ (r & 7);
        bfr[ni] = *reinterpret_cast<const bf16x8*>(Bs + r*64 + s*8);
      }
#pragma unroll
      for (int mi=0;mi<4;mi++)
#pragma unroll
        for (int ni=0;ni<4;ni++)
          acc[mi][ni] = __builtin_amdgcn_mfma_f32_16x16x32_bf16(af[mi], bfr[ni], acc[mi][ni], 0,0,0);
    }
    __syncthreads();
  }

#pragma unroll
  for (int mi=0;mi<4;mi++){
#pragma unroll
    for (int ni=0;ni<4;ni++){
      int col = col0 + wc*64 + ni*16 + lm;
      float bv = bias[col];
#pragma unroll
      for (int j=0;j<4;j++){
        int row = row0 + wr*64 + mi*16 + l4*4 + j;
        C[(size_t)row*N + col] = (OutT)(acc[mi][ni][j] + bv);
      }
    }
  }
}

__global__ void gemm_kernel(const bf16_t* __restrict__ A, const bf16_t* __restrict__ W,
                            const float* __restrict__ bias, float* __restrict__ C,
                            int N, int K){
  __shared__ bf16_t As[128*64];
  __shared__ bf16_t Bs[128*64];
  gemm_body<float>(A, W, bias, C, N, K, blockIdx.x*128, blockIdx.y*128, As, Bs);
}

// fused q-proj + kv-proj: 576 blocks, XCD-bijective remap; bf16 outputs
__global__ void gemm_qkv_kernel(const bf16_t* __restrict__ qn, const bf16_t* __restrict__ kvb,
                                const bf16_t* __restrict__ wq, const bf16_t* __restrict__ wkv,
                                const float* __restrict__ bq, const float* __restrict__ bkv,
                                bf16_t* __restrict__ qp, bf16_t* __restrict__ kvp){
  __shared__ bf16_t As[128*64];
  __shared__ bf16_t Bs[128*64];
  int l = (blockIdx.x & 7)*72 + (blockIdx.x >> 3);  // 576 = 8*72
  int x = l & 31, y = l >> 5;
  if (y < 6)
    gemm_body<bf16_t>(qn,  wq,  bq,  qp,  D_,   D_, x*128, y*128,     As, Bs);
  else
    gemm_body<bf16_t>(kvb, wkv, bkv, kvp, 2*D_, D_, x*128, (y-6)*128, As, Bs);
}

// ---------------- one attention step: QK^T -> exp2 -> P repack -> PV ----------------
__device__ __forceinline__ void attn_step(const bf16x8 (&kf)[4], const bf16x8 (&vf)[4],
                                          const bf16x8 (&qf)[4], f32x16 (&acc_o)[2],
                                          float &psum){
  f32x16 accs = {};
#pragma unroll
  for (int c=0;c<4;c++)
    accs = __builtin_amdgcn_mfma_f32_32x32x16_bf16(kf[c], qf[c], accs, 0,0,0);
#pragma unroll
  for (int r=0;r<16;r++){
    float v = exp2f(accs[r]);
    accs[r] = v;
    psum += v;
  }
  bf16x8 pa[2];
#pragma unroll
  for (int ks=0;ks<2;ks++){
    const int base = ks*8;
    unsigned int a0 = cvtpk(accs[base+0], accs[base+1]);
    unsigned int a1 = cvtpk(accs[base+2], accs[base+3]);
    unsigned int b0 = cvtpk(accs[base+4], accs[base+5]);
    unsigned int b1 = cvtpk(accs[base+6], accs[base+7]);
    plswap(a0, b0);
    plswap(a1, b1);
    u32x4 w; w[0]=a0; w[1]=a1; w[2]=b0; w[3]=b1;
    pa[ks] = __builtin_bit_cast(bf16x8, w);
  }
#pragma unroll
  for (int dt=0;dt<2;dt++)
#pragma unroll
    for (int ks=0;ks<2;ks++)
      acc_o[dt] = __builtin_amdgcn_mfma_f32_32x32x16_bf16(pa[ks], vf[dt*2+ks], acc_o[dt], 0,0,0);
}

// ---------------- flash attention (R13 kernel, best measured; unchanged) ----------------
__global__ __launch_bounds__(256, 3)
void attn_kernel(const bf16_t* __restrict__ Qf, const bf16_t* __restrict__ Kf,
                 const bf16_t* __restrict__ Vf, bf16_t* __restrict__ Oh){
  const int lane = threadIdx.x & 63;
  const int wv   = threadIdx.x >> 6;  // key-quarter 0..3
  const int hi = lane >> 5, lq = lane & 31;
  // XCD-chunked bijective remap: 1536 = 8*192 (6 heads per XCD)
  int l = ((int)blockIdx.x & 7)*192 + ((int)blockIdx.x >> 3);
  const int bh = l >> 5;              // 0..47
  const int qt = l & 31;              // 0..31
  const int q0 = qt*32;
  const int b = bh / H_, h = bh % H_;
  const size_t headoff = ((size_t)b*S_*H_ + h)*HD_;

  __shared__ float part[4][64][33];   // f32 partials, padded (conflict-free)
  __shared__ float ps[4][32];

  bf16x8 qf[4];
  {
    const bf16_t* qp_ = Qf + (size_t)(bh*32 + qt)*2048 + lane*8;
#pragma unroll
    for (int c=0;c<4;c++)
      qf[c] = *reinterpret_cast<const bf16x8*>(qp_ + c*512);
  }

  const bf16_t* kbase = Kf + ((size_t)bh*32 + wv*8)*2048 + lane*8;
  const bf16_t* vbase = Vf + ((size_t)bh*32 + wv*8)*2048 + lane*8;

  float psum = 0.f;
  f32x16 acc_o[2] = {};   // [dt]

  bf16x8 kfA[4], kfB[4], vf[4];
#pragma unroll
  for (int c=0;c<4;c++)
    kfA[c] = *reinterpret_cast<const bf16x8*>(kbase + c*512);

#pragma unroll
  for (int t=0; t<4; ++t){
    {
      const bf16_t* vp = vbase + (size_t)(2*t)*2048;
#pragma unroll
      for (int j=0;j<4;j++) vf[j] = *reinterpret_cast<const bf16x8*>(vp + j*512);
      const bf16_t* kp = kbase + (size_t)(2*t+1)*2048;
#pragma unroll
      for (int c=0;c<4;c++) kfB[c] = *reinterpret_cast<const bf16x8*>(kp + c*512);
      attn_step(kfA, vf, qf, acc_o, psum);
    }
    {
      const bf16_t* vp = vbase + (size_t)(2*t+1)*2048;
#pragma unroll
      for (int j=0;j<4;j++) vf[j] = *reinterpret_cast<const bf16x8*>(vp + j*512);
      if (t < 3){
        const bf16_t* kp = kbase + (size_t)(2*t+2)*2048;
#pragma unroll
        for (int c=0;c<4;c++) kfA[c] = *reinterpret_cast<const bf16x8*>(kp + c*512);
      }
      attn_step(kfB, vf, qf, acc_o, psum);
    }
  }

  float tp = psum + __shfl_xor(psum, 32, 64);
#pragma unroll
  for (int dt=0;dt<2;dt++)
#pragma unroll
    for (int r=0;r<16;r++)
      part[wv][lane][dt*16+r] = acc_o[dt][r];
  if (lane < 32) ps[wv][lq] = tp;
  __syncthreads();

  const int dt = wv >> 1;
  const int rbase = (wv & 1)*8;
  float tot = ps[0][lq] + ps[1][lq] + ps[2][lq] + ps[3][lq];
  float inv = 1.0f / tot;

  bf16_t* obase = Oh + headoff;
#pragma unroll
  for (int ri=0;ri<8;ri++){
    int r = rbase + ri;
    float s = part[0][lane][dt*16+r] + part[1][lane][dt*16+r]
            + part[2][lane][dt*16+r] + part[3][lane][dt*16+r];
    float invr = __shfl(inv, (r&3) + 8*(r>>2) + 4*hi, 64);
    int qq = q0 + (r&3) + 8*(r>>2) + 4*hi;
    obase[(size_t)qq*RSTRIDE + dt*32 + lq] = (bf16_t)(s*invr);
  }
}

// ---------------- launch ----------------
extern "C" void kernel_launch(void* const* d_in, const int* in_sizes, int n_in,
                              void* d_out, int out_size, void* d_ws, size_t ws_size,
                              hipStream_t stream) {
  const float* q      = (const float*)d_in[0];
  const float* kv     = (const float*)d_in[1];
  const int*   posq   = (const int*)d_in[2];
  const int*   posk   = (const int*)d_in[3];
  const float* w_norm = (const float*)d_in[4];
  const float* w_q    = (const float*)d_in[5];
  const float* b_q    = (const float*)d_in[6];
  const float* w_kv   = (const float*)d_in[7];
  const float* b_kv   = (const float*)d_in[8];
  const float* w_out  = (const float*)d_in[9];
  const float* b_out  = (const float*)d_in[10];
  const float* freqs  = (const float*)d_in[11];
  float* out = (float*)d_out;

  char* p = (char*)d_ws;
  bf16_t* qn   = (bf16_t*)p; p += (size_t)NROW*D_*2;
  bf16_t* kvb  = (bf16_t*)p; p += (size_t)NROW*D_*2;
  bf16_t* wqb  = (bf16_t*)p; p += (size_t)D_*D_*2;
  bf16_t* wkvb = (bf16_t*)p; p += (size_t)2*D_*D_*2;
  bf16_t* wob  = (bf16_t*)p; p += (size_t)D_*D_*2;
  bf16_t* qh   = (bf16_t*)p; p += (size_t)NROW*D_*2;    // Q fragments
  bf16_t* kh   = (bf16_t*)p; p += (size_t)NROW*D_*2;    // K fragments
  bf16_t* vt   = (bf16_t*)p; p += (size_t)NBH*HD_*S_*2; // V fragments
  bf16_t* oh   = (bf16_t*)p; p += (size_t)NROW*D_*2;
  bf16_t* qp   = (bf16_t*)p; p += (size_t)NROW*D_*2;    // q-proj (bf16)
  bf16_t* kvp  = (bf16_t*)p; p += (size_t)NROW*2*D_*2;  // kv-proj (bf16)

  // 1) RMSNorm + all casts
  prep_kernel<<<NROW + 5376, 256, 0, stream>>>(q, w_norm, qn,
                                               w_q, wqb, w_kv, wkvb, w_out, wob, kv, kvb);
  // 2) q-proj + kv-proj (fused, XCD-remapped, bf16 out, BK=64 swizzled)
  gemm_qkv_kernel<<<576, 256, 0, stream>>>(qn, kvb, wqb, wkvb, b_q, b_kv, qp, kvp);
  // 3) RoPE(q)+RoPE(k)+V pack into fragment-major layout (bf16 in)
  pack_kernel<<<2*6144 + 1536, 256, 0, stream>>>(qp, posq, kvp, posk, freqs, qh, kh, vt);
  // 4) attention (R13 kernel)
  attn_kernel<<<1536, 256, 0, stream>>>(qh, kh, vt, oh);
  // 5) output projection -> f32 d_out (BK=64 swizzled)
  gemm_kernel<<<dim3(32, 6), 256, 0, stream>>>(oh, wob, b_out, out, D_, D_);
}

// Round 17
// 82.748 us; speedup vs baseline: 1.1508x; 1.0755x over previous
//
#include <hip/hip_runtime.h>

#define B_   4
#define S_   1024
#define D_   768
#define H_   12
#define HD_  64
#define NROW (B_*S_)          // 4096
#define RSTRIDE (H_*HD_)      // 768
#define NBH  (B_*H_)          // 48
#define LOG2E 1.44269504f

typedef __bf16 bf16_t;
typedef bf16_t bf16x8 __attribute__((ext_vector_type(8)));
typedef float  f32x4  __attribute__((ext_vector_type(4)));
typedef float  f32x16 __attribute__((ext_vector_type(16)));
typedef unsigned int u32x4 __attribute__((ext_vector_type(4)));

__device__ __forceinline__ unsigned short bf16b(float f){
  bf16_t b = (bf16_t)f;
  return __builtin_bit_cast(unsigned short, b);
}

__device__ __forceinline__ void gload16(const void* g, void* l){
  __builtin_amdgcn_global_load_lds(
      (const __attribute__((address_space(1))) void*)g,
      (__attribute__((address_space(3))) void*)l, 16, 0, 0);
}

__device__ __forceinline__ unsigned int cvtpk(float lo, float hi){
  unsigned int r;
  asm("v_cvt_pk_bf16_f32 %0, %1, %2" : "=v"(r) : "v"(lo), "v"(hi));
  return r;
}

__device__ __forceinline__ void plswap(unsigned int &a, unsigned int &b){
  asm volatile("v_permlane32_swap_b32 %0, %1" : "+v"(a), "+v"(b));
}

// ---------------- fused prep: RMSNorm(q) + all f32->bf16 casts, one launch ----------------
__global__ void prep_kernel(const float* __restrict__ q, const float* __restrict__ w_norm,
                            bf16_t* __restrict__ qn,
                            const float* __restrict__ wq,  bf16_t* __restrict__ wqb,
                            const float* __restrict__ wkv, bf16_t* __restrict__ wkvb,
                            const float* __restrict__ wo,  bf16_t* __restrict__ wob,
                            const float* __restrict__ kv,  bf16_t* __restrict__ kvb){
  int bid = blockIdx.x;
  if (bid < NROW){
    int row = bid;
    const float* src = q + (size_t)row*D_;
    float vals[3]; float ss = 0.f;
#pragma unroll
    for (int i=0;i<3;i++){ float v = src[threadIdx.x + i*256]; vals[i]=v; ss += v*v; }
#pragma unroll
    for (int m=1;m<64;m<<=1) ss += __shfl_xor(ss, m, 64);
    __shared__ float red[4];
    if ((threadIdx.x & 63) == 0) red[threadIdx.x>>6] = ss;
    __syncthreads();
    float tot = red[0]+red[1]+red[2]+red[3];
    float rs = rsqrtf(tot*(1.0f/D_) + 1e-5f);
#pragma unroll
    for (int i=0;i<3;i++){
      int c = threadIdx.x + i*256;
      qn[(size_t)row*D_ + c] = (bf16_t)(vals[i]*rs*w_norm[c]);
    }
  } else {
    int i = (bid - NROW)*256 + threadIdx.x;
    const int n0 = D_*D_/4, n1 = 2*D_*D_/4, n2 = D_*D_/4, n3 = NROW*D_/4;
    const float* s; bf16_t* d; int off;
    if (i < n0){ s = wq; d = wqb; off = i; }
    else if (i < n0+n1){ s = wkv; d = wkvb; off = i - n0; }
    else if (i < n0+n1+n2){ s = wo; d = wob; off = i - n0 - n1; }
    else if (i < n0+n1+n2+n3){ s = kv; d = kvb; off = i - n0 - n1 - n2; }
    else return;
    float4 v = reinterpret_cast<const float4*>(s)[off];
    ushort4 o;
    o.x = bf16b(v.x); o.y = bf16b(v.y); o.z = bf16b(v.z); o.w = bf16b(v.w);
    reinterpret_cast<ushort4*>(d)[off] = o;
  }
}

// ---------------- bf16 GEMM core, BK=64 swizzled: acc = A[M,K] * W[N,K]^T ----------------
__device__ __forceinline__ void gemm_core(const bf16_t* __restrict__ A, const bf16_t* __restrict__ W,
                                          int K, int row0, int col0,
                                          bf16_t* As, bf16_t* Bs, f32x4 (&acc)[4][4]){
  const int tid  = threadIdx.x;
  const int lane = tid & 63;
  const int wv   = tid >> 6;
  const int wr = wv >> 1, wc = wv & 1;
  const int l4 = lane >> 4, lm = lane & 15;

  for (int kt = 0; kt < K; kt += 64){
#pragma unroll
    for (int i=0;i<4;i++){
      int c = i*256 + tid;
      int r = c >> 3, kc = (c & 7) ^ (r & 7);
      gload16(A + (size_t)(row0+r)*K + kt + kc*8, As + (size_t)(i*256 + wv*64)*8);
    }
#pragma unroll
    for (int i=0;i<4;i++){
      int c = i*256 + tid;
      int r = c >> 3, kc = (c & 7) ^ (r & 7);
      gload16(W + (size_t)(col0+r)*K + kt + kc*8, Bs + (size_t)(i*256 + wv*64)*8);
    }
    __syncthreads();

#pragma unroll
    for (int kk=0; kk<2; kk++){
      bf16x8 af[4], bfr[4];
#pragma unroll
      for (int mi=0;mi<4;mi++){
        int r = wr*64 + mi*16 + lm;
        int s = (kk*4 + l4) ^ (r & 7);
        af[mi] = *reinterpret_cast<const bf16x8*>(As + r*64 + s*8);
      }
#pragma unroll
      for (int ni=0;ni<4;ni++){
        int r = wc*64 + ni*16 + lm;
        int s = (kk*4 + l4) ^ (r & 7);
        bfr[ni] = *reinterpret_cast<const bf16x8*>(Bs + r*64 + s*8);
      }
#pragma unroll
      for (int mi=0;mi<4;mi++)
#pragma unroll
        for (int ni=0;ni<4;ni++)
          acc[mi][ni] = __builtin_amdgcn_mfma_f32_16x16x32_bf16(af[mi], bfr[ni], acc[mi][ni], 0,0,0);
    }
    __syncthreads();
  }
}

// ---------------- out-proj: core + bias + f32 write ----------------
__global__ void gemm_kernel(const bf16_t* __restrict__ A, const bf16_t* __restrict__ W,
                            const float* __restrict__ bias, float* __restrict__ C,
                            int N, int K){
  __shared__ bf16_t As[128*64];
  __shared__ bf16_t Bs[128*64];
  f32x4 acc[4][4] = {};
  gemm_core(A, W, K, blockIdx.x*128, blockIdx.y*128, As, Bs, acc);
  const int lane = threadIdx.x & 63;
  const int wv   = threadIdx.x >> 6;
  const int wr = wv >> 1, wc = wv & 1;
  const int l4 = lane >> 4, lm = lane & 15;
  const int row0 = blockIdx.x*128, col0 = blockIdx.y*128;
#pragma unroll
  for (int mi=0;mi<4;mi++){
#pragma unroll
    for (int ni=0;ni<4;ni++){
      int col = col0 + wc*64 + ni*16 + lm;
      float bv = bias[col];
#pragma unroll
      for (int j=0;j<4;j++){
        int row = row0 + wr*64 + mi*16 + l4*4 + j;
        C[(size_t)row*N + col] = acc[mi][ni][j] + bv;
      }
    }
  }
}

// ---------------- fused epilogue: bias + RoPE + fragment-pack (q or k) ----------------
// col pairs (2f,2f+1) live in adjacent lanes (col=...+lm) -> pair exchange = shfl_xor(1).
// dstfrag layout (= old rope_body): (bh*32+tile)*2048 + cc*512 + hi*256 + lq*8 + (f&3)*2 + par
__device__ __forceinline__ void epi_rope(f32x4 (&acc)[4][4], const float* __restrict__ bias,
                                         const int* __restrict__ pos, const float* __restrict__ freqs,
                                         bf16_t* __restrict__ dst, int row0, int col0, float scale){
  const int lane = threadIdx.x & 63;
  const int wv   = threadIdx.x >> 6;
  const int wr = wv >> 1, wc = wv & 1;
  const int l4 = lane >> 4, lm = lane & 15;
  const int par = lm & 1;
#pragma unroll
  for (int ni=0;ni<4;ni++){
    int col = col0 + wc*64 + ni*16 + lm;
    int h = col >> 6, hd = col & 63, f = hd >> 1;
    float F1 = freqs[h*32 + f];
    float F2 = freqs[H_*32 + h*32 + f];
    float bv = bias[col];
    int cc = f >> 3, hi = (f >> 2) & 1;
    int ebase = cc*512 + hi*256 + (f&3)*2 + par;
#pragma unroll
    for (int mi=0;mi<4;mi++){
#pragma unroll
      for (int j=0;j<4;j++){
        int row = row0 + wr*64 + mi*16 + l4*4 + j;
        float v = acc[mi][ni][j] + bv;
        float vp = __shfl_xor(v, 1, 64);
        float p0 = (float)pos[row*2+0], p1 = (float)pos[row*2+1];
        float ang = p0*F1 + p1*F2;
        float sn, cs;
        __sincosf(ang, &sn, &cs);
        // even lane: xr=v, xi=vp -> v*cs - vp*sn ; odd lane: xr=vp, xi=v -> vp*sn + v*cs
        float out = (par ? (vp*sn + v*cs) : (v*cs - vp*sn)) * scale;
        int b = row >> 10, s = row & 1023;
        int bh = b*H_ + h, tile = s >> 5, lq = s & 31;
        dst[((size_t)(bh*32 + tile))*2048 + ebase + lq*8] = (bf16_t)out;
      }
    }
  }
}

// ---------------- fused epilogue: bias + V fragment-pack (transpose) ----------------
// vfrag (= old pack): (bh*32+kb)*2048 + dt*1024 + ks*512 + hi2*256 + lq2*8 + jj
//   where key=s: kb=s>>5, ks=(s>>4)&1, hi2=(s>>3)&1, jj=s&7 ; d=vcol&63: dt=d>>5, lq2=d&31
__device__ __forceinline__ void epi_vpack(f32x4 (&acc)[4][4], const float* __restrict__ bias,
                                          bf16_t* __restrict__ vfrag, int row0, int col0){
  const int lane = threadIdx.x & 63;
  const int wv   = threadIdx.x >> 6;
  const int wr = wv >> 1, wc = wv & 1;
  const int l4 = lane >> 4, lm = lane & 15;
#pragma unroll
  for (int ni=0;ni<4;ni++){
    int col = col0 + wc*64 + ni*16 + lm;
    int vcol = col - D_;
    int h = vcol >> 6, d = vcol & 63;
    int dt = d >> 5, lq2 = d & 31;
    float bv = bias[col];
    int ebase = dt*1024 + lq2*8;
#pragma unroll
    for (int mi=0;mi<4;mi++){
#pragma unroll
      for (int j=0;j<4;j++){
        int row = row0 + wr*64 + mi*16 + l4*4 + j;
        int b = row >> 10, s = row & 1023;
        int bh = b*H_ + h;
        int kb = s >> 5, ks = (s >> 4) & 1, hi2 = (s >> 3) & 1, jj = s & 7;
        vfrag[((size_t)(bh*32 + kb))*2048 + ebase + ks*512 + hi2*256 + jj]
            = (bf16_t)(acc[mi][ni][j] + bv);
      }
    }
  }
}

// ---------------- fused q-proj + kv-proj + RoPE + pack: 576 blocks, XCD remap ----------------
__global__ void gemm_qkv_kernel(const bf16_t* __restrict__ qn, const bf16_t* __restrict__ kvb,
                                const bf16_t* __restrict__ wq, const bf16_t* __restrict__ wkv,
                                const float* __restrict__ bq, const float* __restrict__ bkv,
                                const int* __restrict__ posq, const int* __restrict__ posk,
                                const float* __restrict__ freqs,
                                bf16_t* __restrict__ qh, bf16_t* __restrict__ kh,
                                bf16_t* __restrict__ vfrag){
  __shared__ bf16_t As[128*64];
  __shared__ bf16_t Bs[128*64];
  int l = (blockIdx.x & 7)*72 + (blockIdx.x >> 3);  // 576 = 8*72
  int x = l & 31, y = l >> 5;                       // x: row tile 0..31, y: col tile 0..17
  f32x4 acc[4][4] = {};
  if (y < 6){
    // q-proj cols [y*128, y*128+128) ; RoPE(posq) with attn scale fold
    gemm_core(qn, wq, D_, x*128, y*128, As, Bs, acc);
    epi_rope(acc, bq, posq, freqs, qh, x*128, y*128, 0.125f*LOG2E);
  } else {
    int c0 = (y-6)*128;                             // kv-proj cols [c0, c0+128) of 1536
    gemm_core(kvb, wkv, D_, x*128, c0, As, Bs, acc);
    if (y < 12)
      epi_rope(acc, bkv, posk, freqs, kh, x*128, c0, 1.0f);   // K half (cols < 768)
    else
      epi_vpack(acc, bkv, vfrag, x*128, c0);                  // V half (cols >= 768)
  }
}

// ---------------- one attention step: QK^T -> exp2 -> P repack -> PV ----------------
__device__ __forceinline__ void attn_step(const bf16x8 (&kf)[4], const bf16x8 (&vf)[4],
                                          const bf16x8 (&qf)[4], f32x16 (&acc_o)[2],
                                          float &psum){
  f32x16 accs = {};
#pragma unroll
  for (int c=0;c<4;c++)
    accs = __builtin_amdgcn_mfma_f32_32x32x16_bf16(kf[c], qf[c], accs, 0,0,0);
#pragma unroll
  for (int r=0;r<16;r++){
    float v = exp2f(accs[r]);
    accs[r] = v;
    psum += v;
  }
  bf16x8 pa[2];
#pragma unroll
  for (int ks=0;ks<2;ks++){
    const int base = ks*8;
    unsigned int a0 = cvtpk(accs[base+0], accs[base+1]);
    unsigned int a1 = cvtpk(accs[base+2], accs[base+3]);
    unsigned int b0 = cvtpk(accs[base+4], accs[base+5]);
    unsigned int b1 = cvtpk(accs[base+6], accs[base+7]);
    plswap(a0, b0);
    plswap(a1, b1);
    u32x4 w; w[0]=a0; w[1]=a1; w[2]=b0; w[3]=b1;
    pa[ks] = __builtin_bit_cast(bf16x8, w);
  }
#pragma unroll
  for (int dt=0;dt<2;dt++)
#pragma unroll
    for (int ks=0;ks<2;ks++)
      acc_o[dt] = __builtin_amdgcn_mfma_f32_32x32x16_bf16(pa[ks], vf[dt*2+ks], acc_o[dt], 0,0,0);
}

// ---------------- flash attention (R13 kernel, best measured; unchanged) ----------------
__global__ __launch_bounds__(256, 3)
void attn_kernel(const bf16_t* __restrict__ Qf, const bf16_t* __restrict__ Kf,
                 const bf16_t* __restrict__ Vf, bf16_t* __restrict__ Oh){
  const int lane = threadIdx.x & 63;
  const int wv   = threadIdx.x >> 6;  // key-quarter 0..3
  const int hi = lane >> 5, lq = lane & 31;
  // XCD-chunked bijective remap: 1536 = 8*192 (6 heads per XCD)
  int l = ((int)blockIdx.x & 7)*192 + ((int)blockIdx.x >> 3);
  const int bh = l >> 5;              // 0..47
  const int qt = l & 31;              // 0..31
  const int q0 = qt*32;
  const int b = bh / H_, h = bh % H_;
  const size_t headoff = ((size_t)b*S_*H_ + h)*HD_;

  __shared__ float part[4][64][33];   // f32 partials, padded (conflict-free)
  __shared__ float ps[4][32];

  bf16x8 qf[4];
  {
    const bf16_t* qp_ = Qf + (size_t)(bh*32 + qt)*2048 + lane*8;
#pragma unroll
    for (int c=0;c<4;c++)
      qf[c] = *reinterpret_cast<const bf16x8*>(qp_ + c*512);
  }

  const bf16_t* kbase = Kf + ((size_t)bh*32 + wv*8)*2048 + lane*8;
  const bf16_t* vbase = Vf + ((size_t)bh*32 + wv*8)*2048 + lane*8;

  float psum = 0.f;
  f32x16 acc_o[2] = {};   // [dt]

  bf16x8 kfA[4], kfB[4], vf[4];
#pragma unroll
  for (int c=0;c<4;c++)
    kfA[c] = *reinterpret_cast<const bf16x8*>(kbase + c*512);

#pragma unroll
  for (int t=0; t<4; ++t){
    {
      const bf16_t* vp = vbase + (size_t)(2*t)*2048;
#pragma unroll
      for (int j=0;j<4;j++) vf[j] = *reinterpret_cast<const bf16x8*>(vp + j*512);
      const bf16_t* kp = kbase + (size_t)(2*t+1)*2048;
#pragma unroll
      for (int c=0;c<4;c++) kfB[c] = *reinterpret_cast<const bf16x8*>(kp + c*512);
      attn_step(kfA, vf, qf, acc_o, psum);
    }
    {
      const bf16_t* vp = vbase + (size_t)(2*t+1)*2048;
#pragma unroll
      for (int j=0;j<4;j++) vf[j] = *reinterpret_cast<const bf16x8*>(vp + j*512);
      if (t < 3){
        const bf16_t* kp = kbase + (size_t)(2*t+2)*2048;
#pragma unroll
        for (int c=0;c<4;c++) kfA[c] = *reinterpret_cast<const bf16x8*>(kp + c*512);
      }
      attn_step(kfB, vf, qf, acc_o, psum);
    }
  }

  float tp = psum + __shfl_xor(psum, 32, 64);
#pragma unroll
  for (int dt=0;dt<2;dt++)
#pragma unroll
    for (int r=0;r<16;r++)
      part[wv][lane][dt*16+r] = acc_o[dt][r];
  if (lane < 32) ps[wv][lq] = tp;
  __syncthreads();

  const int dt = wv >> 1;
  const int rbase = (wv & 1)*8;
  float tot = ps[0][lq] + ps[1][lq] + ps[2][lq] + ps[3][lq];
  float inv = 1.0f / tot;

  bf16_t* obase = Oh + headoff;
#pragma unroll
  for (int ri=0;ri<8;ri++){
    int r = rbase + ri;
    float s = part[0][lane][dt*16+r] + part[1][lane][dt*16+r]
            + part[2][lane][dt*16+r] + part[3][lane][dt*16+r];
    float invr = __shfl(inv, (r&3) + 8*(r>>2) + 4*hi, 64);
    int qq = q0 + (r&3) + 8*(r>>2) + 4*hi;
    obase[(size_t)qq*RSTRIDE + dt*32 + lq] = (bf16_t)(s*invr);
  }
}

// ---------------- launch ----------------
extern "C" void kernel_launch(void* const* d_in, const int* in_sizes, int n_in,
                              void* d_out, int out_size, void* d_ws, size_t ws_size,
                              hipStream_t stream) {
  const float* q      = (const float*)d_in[0];
  const float* kv     = (const float*)d_in[1];
  const int*   posq   = (const int*)d_in[2];
  const int*   posk   = (const int*)d_in[3];
  const float* w_norm = (const float*)d_in[4];
  const float* w_q    = (const float*)d_in[5];
  const float* b_q    = (const float*)d_in[6];
  const float* w_kv   = (const float*)d_in[7];
  const float* b_kv   = (const float*)d_in[8];
  const float* w_out  = (const float*)d_in[9];
  const float* b_out  = (const float*)d_in[10];
  const float* freqs  = (const float*)d_in[11];
  float* out = (float*)d_out;

  char* p = (char*)d_ws;
  bf16_t* qn   = (bf16_t*)p; p += (size_t)NROW*D_*2;
  bf16_t* kvb  = (bf16_t*)p; p += (size_t)NROW*D_*2;
  bf16_t* wqb  = (bf16_t*)p; p += (size_t)D_*D_*2;
  bf16_t* wkvb = (bf16_t*)p; p += (size_t)2*D_*D_*2;
  bf16_t* wob  = (bf16_t*)p; p += (size_t)D_*D_*2;
  bf16_t* qh   = (bf16_t*)p; p += (size_t)NROW*D_*2;    // Q fragments
  bf16_t* kh   = (bf16_t*)p; p += (size_t)NROW*D_*2;    // K fragments
  bf16_t* vt   = (bf16_t*)p; p += (size_t)NBH*HD_*S_*2; // V fragments
  bf16_t* oh   = (bf16_t*)p; p += (size_t)NROW*D_*2;

  // 1) RMSNorm + all casts
  prep_kernel<<<NROW + 5376, 256, 0, stream>>>(q, w_norm, qn,
                                               w_q, wqb, w_kv, wkvb, w_out, wob, kv, kvb);
  // 2) q-proj + kv-proj GEMM with fused bias+RoPE+fragment-pack epilogues
  //    (q scale = 1/sqrt(64) * log2(e) folded so attention uses exp2 directly)
  gemm_qkv_kernel<<<576, 256, 0, stream>>>(qn, kvb, wqb, wkvb, b_q, b_kv,
                                           posq, posk, freqs, qh, kh, vt);
  // 3) attention (R13 kernel: reg-pipelined, in-block split-K=4)
  attn_kernel<<<1536, 256, 0, stream>>>(qh, kh, vt, oh);
  // 4) output projection -> f32 d_out
  gemm_kernel<<<dim3(32, 6), 256, 0, stream>>>(oh, wob, b_out, out, D_, D_);
}

// Round 18
// 76.311 us; speedup vs baseline: 1.2478x; 1.0844x over previous
//
#include <hip/hip_runtime.h>

#define B_   4
#define S_   1024
#define D_   768
#define H_   12
#define HD_  64
#define NROW (B_*S_)          // 4096
#define RSTRIDE (H_*HD_)      // 768
#define NBH  (B_*H_)          // 48
#define LOG2E 1.44269504f

typedef __bf16 bf16_t;
typedef bf16_t bf16x8 __attribute__((ext_vector_type(8)));
typedef float  f32x4  __attribute__((ext_vector_type(4)));
typedef float  f32x16 __attribute__((ext_vector_type(16)));
typedef unsigned int u32x4 __attribute__((ext_vector_type(4)));

__device__ __forceinline__ unsigned short bf16b(float f){
  bf16_t b = (bf16_t)f;
  return __builtin_bit_cast(unsigned short, b);
}

__device__ __forceinline__ void gload16(const void* g, void* l){
  __builtin_amdgcn_global_load_lds(
      (const __attribute__((address_space(1))) void*)g,
      (__attribute__((address_space(3))) void*)l, 16, 0, 0);
}

__device__ __forceinline__ unsigned int cvtpk(float lo, float hi){
  unsigned int r;
  asm("v_cvt_pk_bf16_f32 %0, %1, %2" : "=v"(r) : "v"(lo), "v"(hi));
  return r;
}

__device__ __forceinline__ void plswap(unsigned int &a, unsigned int &b){
  asm volatile("v_permlane32_swap_b32 %0, %1" : "+v"(a), "+v"(b));
}

// ---------------- fused prep: RMSNorm(q) + all f32->bf16 casts, one launch ----------------
__global__ void prep_kernel(const float* __restrict__ q, const float* __restrict__ w_norm,
                            bf16_t* __restrict__ qn,
                            const float* __restrict__ wq,  bf16_t* __restrict__ wqb,
                            const float* __restrict__ wkv, bf16_t* __restrict__ wkvb,
                            const float* __restrict__ wo,  bf16_t* __restrict__ wob,
                            const float* __restrict__ kv,  bf16_t* __restrict__ kvb){
  int bid = blockIdx.x;
  if (bid < NROW){
    int row = bid;
    const float* src = q + (size_t)row*D_;
    float vals[3]; float ss = 0.f;
#pragma unroll
    for (int i=0;i<3;i++){ float v = src[threadIdx.x + i*256]; vals[i]=v; ss += v*v; }
#pragma unroll
    for (int m=1;m<64;m<<=1) ss += __shfl_xor(ss, m, 64);
    __shared__ float red[4];
    if ((threadIdx.x & 63) == 0) red[threadIdx.x>>6] = ss;
    __syncthreads();
    float tot = red[0]+red[1]+red[2]+red[3];
    float rs = rsqrtf(tot*(1.0f/D_) + 1e-5f);
#pragma unroll
    for (int i=0;i<3;i++){
      int c = threadIdx.x + i*256;
      qn[(size_t)row*D_ + c] = (bf16_t)(vals[i]*rs*w_norm[c]);
    }
  } else {
    int i = (bid - NROW)*256 + threadIdx.x;
    const int n0 = D_*D_/4, n1 = 2*D_*D_/4, n2 = D_*D_/4, n3 = NROW*D_/4;
    const float* s; bf16_t* d; int off;
    if (i < n0){ s = wq; d = wqb; off = i; }
    else if (i < n0+n1){ s = wkv; d = wkvb; off = i - n0; }
    else if (i < n0+n1+n2){ s = wo; d = wob; off = i - n0 - n1; }
    else if (i < n0+n1+n2+n3){ s = kv; d = kvb; off = i - n0 - n1 - n2; }
    else return;
    float4 v = reinterpret_cast<const float4*>(s)[off];
    ushort4 o;
    o.x = bf16b(v.x); o.y = bf16b(v.y); o.z = bf16b(v.z); o.w = bf16b(v.w);
    reinterpret_cast<ushort4*>(d)[off] = o;
  }
}

// ---------------- templated bf16 GEMM core, BK=64 swizzled, 256 thr, 2x2 waves ----------------
// Tile TM x TN; wave tile (TM/2)x(TN/2); acc[TM/32][TN/32].
template<int TM, int TN>
__device__ __forceinline__ void gemm_core_t(const bf16_t* __restrict__ A, const bf16_t* __restrict__ W,
                                            int K, int row0, int col0,
                                            bf16_t* As, bf16_t* Bs,
                                            f32x4 (&acc)[TM/32][TN/32]){
  const int tid  = threadIdx.x;
  const int lane = tid & 63;
  const int wv   = tid >> 6;
  const int wr = wv >> 1, wc = wv & 1;
  const int l4 = lane >> 4, lm = lane & 15;

  for (int kt = 0; kt < K; kt += 64){
#pragma unroll
    for (int i=0;i<TM/32;i++){
      int c = i*256 + tid;
      int r = c >> 3, kc = (c & 7) ^ (r & 7);
      gload16(A + (size_t)(row0+r)*K + kt + kc*8, As + (size_t)(i*256 + wv*64)*8);
    }
#pragma unroll
    for (int i=0;i<TN/32;i++){
      int c = i*256 + tid;
      int r = c >> 3, kc = (c & 7) ^ (r & 7);
      gload16(W + (size_t)(col0+r)*K + kt + kc*8, Bs + (size_t)(i*256 + wv*64)*8);
    }
    __syncthreads();

#pragma unroll
    for (int kk=0; kk<2; kk++){
      bf16x8 af[TM/32], bfr[TN/32];
#pragma unroll
      for (int mi=0;mi<TM/32;mi++){
        int r = wr*(TM/2) + mi*16 + lm;
        int s = (kk*4 + l4) ^ (r & 7);
        af[mi] = *reinterpret_cast<const bf16x8*>(As + r*64 + s*8);
      }
#pragma unroll
      for (int ni=0;ni<TN/32;ni++){
        int r = wc*(TN/2) + ni*16 + lm;
        int s = (kk*4 + l4) ^ (r & 7);
        bfr[ni] = *reinterpret_cast<const bf16x8*>(Bs + r*64 + s*8);
      }
#pragma unroll
      for (int mi=0;mi<TM/32;mi++)
#pragma unroll
        for (int ni=0;ni<TN/32;ni++)
          acc[mi][ni] = __builtin_amdgcn_mfma_f32_16x16x32_bf16(af[mi], bfr[ni], acc[mi][ni], 0,0,0);
    }
    __syncthreads();
  }
}

// ---------------- out-proj: 64x64 tiles (768 blocks = 3/CU), bias + f32 write ----------------
__global__ void gemm_kernel(const bf16_t* __restrict__ A, const bf16_t* __restrict__ W,
                            const float* __restrict__ bias, float* __restrict__ C,
                            int N, int K){
  __shared__ bf16_t As[64*64];
  __shared__ bf16_t Bs[64*64];
  // XCD remap: 768 = 8*96
  int l = ((int)blockIdx.x & 7)*96 + ((int)blockIdx.x >> 3);
  int x = l & 63, y = l >> 6;       // 64 row tiles x 12 col tiles
  f32x4 acc[2][2] = {};
  gemm_core_t<64,64>(A, W, K, x*64, y*64, As, Bs, acc);
  const int lane = threadIdx.x & 63;
  const int wv   = threadIdx.x >> 6;
  const int wr = wv >> 1, wc = wv & 1;
  const int l4 = lane >> 4, lm = lane & 15;
  const int row0 = x*64, col0 = y*64;
#pragma unroll
  for (int mi=0;mi<2;mi++){
#pragma unroll
    for (int ni=0;ni<2;ni++){
      int col = col0 + wc*32 + ni*16 + lm;
      float bv = bias[col];
#pragma unroll
      for (int j=0;j<4;j++){
        int row = row0 + wr*32 + mi*16 + l4*4 + j;
        C[(size_t)row*N + col] = acc[mi][ni][j] + bv;
      }
    }
  }
}

// ---------------- fused epilogue: bias + RoPE + fragment-pack (q or k), TM=64/TN=128 ----------------
// col pairs (2f,2f+1) in adjacent lanes -> pair exchange = shfl_xor(1).
// dstfrag: (bh*32+tile)*2048 + cc*512 + hi*256 + lq*8 + (f&3)*2 + par
__device__ __forceinline__ void epi_rope(f32x4 (&acc)[2][4], const float* __restrict__ bias,
                                         const int* __restrict__ pos, const float* __restrict__ freqs,
                                         bf16_t* __restrict__ dst, int row0, int col0, float scale){
  const int lane = threadIdx.x & 63;
  const int wv   = threadIdx.x >> 6;
  const int wr = wv >> 1, wc = wv & 1;
  const int l4 = lane >> 4, lm = lane & 15;
  const int par = lm & 1;
#pragma unroll
  for (int ni=0;ni<4;ni++){
    int col = col0 + wc*64 + ni*16 + lm;
    int h = col >> 6, hd = col & 63, f = hd >> 1;
    float F1 = freqs[h*32 + f];
    float F2 = freqs[H_*32 + h*32 + f];
    float bv = bias[col];
    int cc = f >> 3, hi = (f >> 2) & 1;
    int ebase = cc*512 + hi*256 + (f&3)*2 + par;
#pragma unroll
    for (int mi=0;mi<2;mi++){
#pragma unroll
      for (int j=0;j<4;j++){
        int row = row0 + wr*32 + mi*16 + l4*4 + j;
        float v = acc[mi][ni][j] + bv;
        float vp = __shfl_xor(v, 1, 64);
        float p0 = (float)pos[row*2+0], p1 = (float)pos[row*2+1];
        float ang = p0*F1 + p1*F2;
        float sn, cs;
        __sincosf(ang, &sn, &cs);
        float out = (par ? (vp*sn + v*cs) : (v*cs - vp*sn)) * scale;
        int b = row >> 10, s = row & 1023;
        int bh = b*H_ + h, tile = s >> 5, lq = s & 31;
        dst[((size_t)(bh*32 + tile))*2048 + ebase + lq*8] = (bf16_t)out;
      }
    }
  }
}

// ---------------- fused epilogue: bias + V fragment-pack (transpose), TM=64/TN=128 ----------------
// vfrag: (bh*32+kb)*2048 + dt*1024 + ks*512 + hi2*256 + lq2*8 + jj
__device__ __forceinline__ void epi_vpack(f32x4 (&acc)[2][4], const float* __restrict__ bias,
                                          bf16_t* __restrict__ vfrag, int row0, int col0){
  const int lane = threadIdx.x & 63;
  const int wv   = threadIdx.x >> 6;
  const int wr = wv >> 1, wc = wv & 1;
  const int l4 = lane >> 4, lm = lane & 15;
#pragma unroll
  for (int ni=0;ni<4;ni++){
    int col = col0 + wc*64 + ni*16 + lm;
    int vcol = col - D_;
    int h = vcol >> 6, d = vcol & 63;
    int dt = d >> 5, lq2 = d & 31;
    float bv = bias[col];
    int ebase = dt*1024 + lq2*8;
#pragma unroll
    for (int mi=0;mi<2;mi++){
#pragma unroll
      for (int j=0;j<4;j++){
        int row = row0 + wr*32 + mi*16 + l4*4 + j;
        int b = row >> 10, s = row & 1023;
        int bh = b*H_ + h;
        int kb = s >> 5, ks = (s >> 4) & 1, hi2 = (s >> 3) & 1, jj = s & 7;
        vfrag[((size_t)(bh*32 + kb))*2048 + ebase + ks*512 + hi2*256 + jj]
            = (bf16_t)(acc[mi][ni][j] + bv);
      }
    }
  }
}

// ---------------- fused q-proj + kv-proj + RoPE + pack: 64x128 tiles, 1152 blocks ----------------
__global__ void gemm_qkv_kernel(const bf16_t* __restrict__ qn, const bf16_t* __restrict__ kvb,
                                const bf16_t* __restrict__ wq, const bf16_t* __restrict__ wkv,
                                const float* __restrict__ bq, const float* __restrict__ bkv,
                                const int* __restrict__ posq, const int* __restrict__ posk,
                                const float* __restrict__ freqs,
                                bf16_t* __restrict__ qh, bf16_t* __restrict__ kh,
                                bf16_t* __restrict__ vfrag){
  __shared__ bf16_t As[64*64];
  __shared__ bf16_t Bs[128*64];
  // XCD remap: 1152 = 8*144
  int l = ((int)blockIdx.x & 7)*144 + ((int)blockIdx.x >> 3);
  int x = l & 63, y = l >> 6;       // x: 64 row tiles (64 rows), y: 18 col tiles (128 cols)
  f32x4 acc[2][4] = {};
  if (y < 6){
    gemm_core_t<64,128>(qn, wq, D_, x*64, y*128, As, Bs, acc);
    epi_rope(acc, bq, posq, freqs, qh, x*64, y*128, 0.125f*LOG2E);
  } else {
    int c0 = (y-6)*128;
    gemm_core_t<64,128>(kvb, wkv, D_, x*64, c0, As, Bs, acc);
    if (y < 12)
      epi_rope(acc, bkv, posk, freqs, kh, x*64, c0, 1.0f);   // K half
    else
      epi_vpack(acc, bkv, vfrag, x*64, c0);                  // V half
  }
}

// ---------------- one attention step: QK^T -> exp2 -> P repack -> PV ----------------
__device__ __forceinline__ void attn_step(const bf16x8 (&kf)[4], const bf16x8 (&vf)[4],
                                          const bf16x8 (&qf)[4], f32x16 (&acc_o)[2],
                                          float &psum){
  f32x16 accs = {};
#pragma unroll
  for (int c=0;c<4;c++)
    accs = __builtin_amdgcn_mfma_f32_32x32x16_bf16(kf[c], qf[c], accs, 0,0,0);
#pragma unroll
  for (int r=0;r<16;r++){
    float v = exp2f(accs[r]);
    accs[r] = v;
    psum += v;
  }
  bf16x8 pa[2];
#pragma unroll
  for (int ks=0;ks<2;ks++){
    const int base = ks*8;
    unsigned int a0 = cvtpk(accs[base+0], accs[base+1]);
    unsigned int a1 = cvtpk(accs[base+2], accs[base+3]);
    unsigned int b0 = cvtpk(accs[base+4], accs[base+5]);
    unsigned int b1 = cvtpk(accs[base+6], accs[base+7]);
    plswap(a0, b0);
    plswap(a1, b1);
    u32x4 w; w[0]=a0; w[1]=a1; w[2]=b0; w[3]=b1;
    pa[ks] = __builtin_bit_cast(bf16x8, w);
  }
#pragma unroll
  for (int dt=0;dt<2;dt++)
#pragma unroll
    for (int ks=0;ks<2;ks++)
      acc_o[dt] = __builtin_amdgcn_mfma_f32_32x32x16_bf16(pa[ks], vf[dt*2+ks], acc_o[dt], 0,0,0);
}

// ---------------- flash attention (R13 kernel, unchanged) ----------------
__global__ __launch_bounds__(256, 3)
void attn_kernel(const bf16_t* __restrict__ Qf, const bf16_t* __restrict__ Kf,
                 const bf16_t* __restrict__ Vf, bf16_t* __restrict__ Oh){
  const int lane = threadIdx.x & 63;
  const int wv   = threadIdx.x >> 6;  // key-quarter 0..3
  const int hi = lane >> 5, lq = lane & 31;
  int l = ((int)blockIdx.x & 7)*192 + ((int)blockIdx.x >> 3);
  const int bh = l >> 5;
  const int qt = l & 31;
  const int q0 = qt*32;
  const int b = bh / H_, h = bh % H_;
  const size_t headoff = ((size_t)b*S_*H_ + h)*HD_;

  __shared__ float part[4][64][33];
  __shared__ float ps[4][32];

  bf16x8 qf[4];
  {
    const bf16_t* qp_ = Qf + (size_t)(bh*32 + qt)*2048 + lane*8;
#pragma unroll
    for (int c=0;c<4;c++)
      qf[c] = *reinterpret_cast<const bf16x8*>(qp_ + c*512);
  }

  const bf16_t* kbase = Kf + ((size_t)bh*32 + wv*8)*2048 + lane*8;
  const bf16_t* vbase = Vf + ((size_t)bh*32 + wv*8)*2048 + lane*8;

  float psum = 0.f;
  f32x16 acc_o[2] = {};

  bf16x8 kfA[4], kfB[4], vf[4];
#pragma unroll
  for (int c=0;c<4;c++)
    kfA[c] = *reinterpret_cast<const bf16x8*>(kbase + c*512);

#pragma unroll
  for (int t=0; t<4; ++t){
    {
      const bf16_t* vp = vbase + (size_t)(2*t)*2048;
#pragma unroll
      for (int j=0;j<4;j++) vf[j] = *reinterpret_cast<const bf16x8*>(vp + j*512);
      const bf16_t* kp = kbase + (size_t)(2*t+1)*2048;
#pragma unroll
      for (int c=0;c<4;c++) kfB[c] = *reinterpret_cast<const bf16x8*>(kp + c*512);
      attn_step(kfA, vf, qf, acc_o, psum);
    }
    {
      const bf16_t* vp = vbase + (size_t)(2*t+1)*2048;
#pragma unroll
      for (int j=0;j<4;j++) vf[j] = *reinterpret_cast<const bf16x8*>(vp + j*512);
      if (t < 3){
        const bf16_t* kp = kbase + (size_t)(2*t+2)*2048;
#pragma unroll
        for (int c=0;c<4;c++) kfA[c] = *reinterpret_cast<const bf16x8*>(kp + c*512);
      }
      attn_step(kfB, vf, qf, acc_o, psum);
    }
  }

  float tp = psum + __shfl_xor(psum, 32, 64);
#pragma unroll
  for (int dt=0;dt<2;dt++)
#pragma unroll
    for (int r=0;r<16;r++)
      part[wv][lane][dt*16+r] = acc_o[dt][r];
  if (lane < 32) ps[wv][lq] = tp;
  __syncthreads();

  const int dt = wv >> 1;
  const int rbase = (wv & 1)*8;
  float tot = ps[0][lq] + ps[1][lq] + ps[2][lq] + ps[3][lq];
  float inv = 1.0f / tot;

  bf16_t* obase = Oh + headoff;
#pragma unroll
  for (int ri=0;ri<8;ri++){
    int r = rbase + ri;
    float s = part[0][lane][dt*16+r] + part[1][lane][dt*16+r]
            + part[2][lane][dt*16+r] + part[3][lane][dt*16+r];
    float invr = __shfl(inv, (r&3) + 8*(r>>2) + 4*hi, 64);
    int qq = q0 + (r&3) + 8*(r>>2) + 4*hi;
    obase[(size_t)qq*RSTRIDE + dt*32 + lq] = (bf16_t)(s*invr);
  }
}

// ---------------- launch ----------------
extern "C" void kernel_launch(void* const* d_in, const int* in_sizes, int n_in,
                              void* d_out, int out_size, void* d_ws, size_t ws_size,
                              hipStream_t stream) {
  const float* q      = (const float*)d_in[0];
  const float* kv     = (const float*)d_in[1];
  const int*   posq   = (const int*)d_in[2];
  const int*   posk   = (const int*)d_in[3];
  const float* w_norm = (const float*)d_in[4];
  const float* w_q    = (const float*)d_in[5];
  const float* b_q    = (const float*)d_in[6];
  const float* w_kv   = (const float*)d_in[7];
  const float* b_kv   = (const float*)d_in[8];
  const float* w_out  = (const float*)d_in[9];
  const float* b_out  = (const float*)d_in[10];
  const float* freqs  = (const float*)d_in[11];
  float* out = (float*)d_out;

  char* p = (char*)d_ws;
  bf16_t* qn   = (bf16_t*)p; p += (size_t)NROW*D_*2;
  bf16_t* kvb  = (bf16_t*)p; p += (size_t)NROW*D_*2;
  bf16_t* wqb  = (bf16_t*)p; p += (size_t)D_*D_*2;
  bf16_t* wkvb = (bf16_t*)p; p += (size_t)2*D_*D_*2;
  bf16_t* wob  = (bf16_t*)p; p += (size_t)D_*D_*2;
  bf16_t* qh   = (bf16_t*)p; p += (size_t)NROW*D_*2;    // Q fragments
  bf16_t* kh   = (bf16_t*)p; p += (size_t)NROW*D_*2;    // K fragments
  bf16_t* vt   = (bf16_t*)p; p += (size_t)NBH*HD_*S_*2; // V fragments
  bf16_t* oh   = (bf16_t*)p; p += (size_t)NROW*D_*2;

  // 1) RMSNorm + all casts
  prep_kernel<<<NROW + 5376, 256, 0, stream>>>(q, w_norm, qn,
                                               w_q, wqb, w_kv, wkvb, w_out, wob, kv, kvb);
  // 2) q-proj + kv-proj GEMM (64x128 tiles, 1152 blocks) + fused RoPE/pack epilogues
  gemm_qkv_kernel<<<1152, 256, 0, stream>>>(qn, kvb, wqb, wkvb, b_q, b_kv,
                                            posq, posk, freqs, qh, kh, vt);
  // 3) attention (R13 kernel)
  attn_kernel<<<1536, 256, 0, stream>>>(qh, kh, vt, oh);
  // 4) output projection (64x64 tiles, 768 blocks) -> f32 d_out
  gemm_kernel<<<768, 256, 0, stream>>>(oh, wob, b_out, out, D_, D_);
}

// Round 19
// 74.728 us; speedup vs baseline: 1.2743x; 1.0212x over previous
//
#include <hip/hip_runtime.h>

#define B_   4
#define S_   1024
#define D_   768
#define H_   12
#define HD_  64
#define NROW (B_*S_)          // 4096
#define RSTRIDE (H_*HD_)      // 768
#define NBH  (B_*H_)          // 48
#define LOG2E 1.44269504f

typedef __bf16 bf16_t;
typedef bf16_t bf16x8 __attribute__((ext_vector_type(8)));
typedef float  f32x4  __attribute__((ext_vector_type(4)));
typedef float  f32x16 __attribute__((ext_vector_type(16)));
typedef unsigned int u32x4 __attribute__((ext_vector_type(4)));

__device__ __forceinline__ unsigned short bf16b(float f){
  bf16_t b = (bf16_t)f;
  return __builtin_bit_cast(unsigned short, b);
}

__device__ __forceinline__ void gload16(const void* g, void* l){
  __builtin_amdgcn_global_load_lds(
      (const __attribute__((address_space(1))) void*)g,
      (__attribute__((address_space(3))) void*)l, 16, 0, 0);
}

__device__ __forceinline__ unsigned int cvtpk(float lo, float hi){
  unsigned int r;
  asm("v_cvt_pk_bf16_f32 %0, %1, %2" : "=v"(r) : "v"(lo), "v"(hi));
  return r;
}

__device__ __forceinline__ void plswap(unsigned int &a, unsigned int &b){
  asm volatile("v_permlane32_swap_b32 %0, %1" : "+v"(a), "+v"(b));
}

// ---------------- fused prep: RMSNorm(q) + all f32->bf16 casts, one launch ----------------
__global__ void prep_kernel(const float* __restrict__ q, const float* __restrict__ w_norm,
                            bf16_t* __restrict__ qn,
                            const float* __restrict__ wq,  bf16_t* __restrict__ wqb,
                            const float* __restrict__ wkv, bf16_t* __restrict__ wkvb,
                            const float* __restrict__ wo,  bf16_t* __restrict__ wob,
                            const float* __restrict__ kv,  bf16_t* __restrict__ kvb){
  int bid = blockIdx.x;
  if (bid < NROW){
    int row = bid;
    const float* src = q + (size_t)row*D_;
    float vals[3]; float ss = 0.f;
#pragma unroll
    for (int i=0;i<3;i++){ float v = src[threadIdx.x + i*256]; vals[i]=v; ss += v*v; }
#pragma unroll
    for (int m=1;m<64;m<<=1) ss += __shfl_xor(ss, m, 64);
    __shared__ float red[4];
    if ((threadIdx.x & 63) == 0) red[threadIdx.x>>6] = ss;
    __syncthreads();
    float tot = red[0]+red[1]+red[2]+red[3];
    float rs = rsqrtf(tot*(1.0f/D_) + 1e-5f);
#pragma unroll
    for (int i=0;i<3;i++){
      int c = threadIdx.x + i*256;
      qn[(size_t)row*D_ + c] = (bf16_t)(vals[i]*rs*w_norm[c]);
    }
  } else {
    int i = (bid - NROW)*256 + threadIdx.x;
    const int n0 = D_*D_/4, n1 = 2*D_*D_/4, n2 = D_*D_/4, n3 = NROW*D_/4;
    const float* s; bf16_t* d; int off;
    if (i < n0){ s = wq; d = wqb; off = i; }
    else if (i < n0+n1){ s = wkv; d = wkvb; off = i - n0; }
    else if (i < n0+n1+n2){ s = wo; d = wob; off = i - n0 - n1; }
    else if (i < n0+n1+n2+n3){ s = kv; d = kvb; off = i - n0 - n1 - n2; }
    else return;
    float4 v = reinterpret_cast<const float4*>(s)[off];
    ushort4 o;
    o.x = bf16b(v.x); o.y = bf16b(v.y); o.z = bf16b(v.z); o.w = bf16b(v.w);
    reinterpret_cast<ushort4*>(d)[off] = o;
  }
}

// ---------------- GEMM building blocks: BK=64 swizzled, 256 thr, 2x2 waves ----------------
template<int TM, int TN>
__device__ __forceinline__ void stage_t(const bf16_t* __restrict__ A, const bf16_t* __restrict__ W,
                                        int K, int row0, int col0, int kt,
                                        bf16_t* As, bf16_t* Bs){
  const int tid = threadIdx.x;
  const int wv  = tid >> 6;
#pragma unroll
  for (int i=0;i<TM/32;i++){
    int c = i*256 + tid;
    int r = c >> 3, kc = (c & 7) ^ (r & 7);
    gload16(A + (size_t)(row0+r)*K + kt + kc*8, As + (size_t)(i*256 + wv*64)*8);
  }
#pragma unroll
  for (int i=0;i<TN/32;i++){
    int c = i*256 + tid;
    int r = c >> 3, kc = (c & 7) ^ (r & 7);
    gload16(W + (size_t)(col0+r)*K + kt + kc*8, Bs + (size_t)(i*256 + wv*64)*8);
  }
}

template<int TM, int TN>
__device__ __forceinline__ void compute_t(const bf16_t* As, const bf16_t* Bs,
                                          f32x4 (&acc)[TM/32][TN/32]){
  const int lane = threadIdx.x & 63;
  const int wv   = threadIdx.x >> 6;
  const int wr = wv >> 1, wc = wv & 1;
  const int l4 = lane >> 4, lm = lane & 15;
#pragma unroll
  for (int kk=0; kk<2; kk++){
    bf16x8 af[TM/32], bfr[TN/32];
#pragma unroll
    for (int mi=0;mi<TM/32;mi++){
      int r = wr*(TM/2) + mi*16 + lm;
      int s = (kk*4 + l4) ^ (r & 7);
      af[mi] = *reinterpret_cast<const bf16x8*>(As + r*64 + s*8);
    }
#pragma unroll
    for (int ni=0;ni<TN/32;ni++){
      int r = wc*(TN/2) + ni*16 + lm;
      int s = (kk*4 + l4) ^ (r & 7);
      bfr[ni] = *reinterpret_cast<const bf16x8*>(Bs + r*64 + s*8);
    }
#pragma unroll
    for (int mi=0;mi<TM/32;mi++)
#pragma unroll
      for (int ni=0;ni<TN/32;ni++)
        acc[mi][ni] = __builtin_amdgcn_mfma_f32_16x16x32_bf16(af[mi], bfr[ni], acc[mi][ni], 0,0,0);
  }
}

// Double-buffered core (T3-minimum 2-phase): issue STAGE(t+1) BEFORE compute(t);
// single __syncthreads() per tile drains the in-flight loads (which had the whole
// MFMA phase to land) instead of the full staging latency sitting on the path.
template<int TM, int TN>
__device__ __forceinline__ void gemm_core_db(const bf16_t* __restrict__ A, const bf16_t* __restrict__ W,
                                             int K, int row0, int col0,
                                             bf16_t* As0, bf16_t* As1, bf16_t* Bs0, bf16_t* Bs1,
                                             f32x4 (&acc)[TM/32][TN/32]){
  stage_t<TM,TN>(A, W, K, row0, col0, 0, As0, Bs0);
  __syncthreads();
  const int nt = K/64;
  bf16_t *Ac = As0, *An = As1, *Bc = Bs0, *Bn = Bs1;
  for (int t=0; t<nt; ++t){
    if (t+1 < nt)
      stage_t<TM,TN>(A, W, K, row0, col0, (t+1)*64, An, Bn);
    compute_t<TM,TN>(Ac, Bc, acc);
    __syncthreads();
    bf16_t* tmp;
    tmp = Ac; Ac = An; An = tmp;
    tmp = Bc; Bc = Bn; Bn = tmp;
  }
}

// ---------------- out-proj: 64x64 tiles, dbuf (768 blocks), bias + f32 write ----------------
__global__ void gemm_kernel(const bf16_t* __restrict__ A, const bf16_t* __restrict__ W,
                            const float* __restrict__ bias, float* __restrict__ C,
                            int N, int K){
  __shared__ bf16_t As[2][64*64];
  __shared__ bf16_t Bs[2][64*64];
  int l = ((int)blockIdx.x & 7)*96 + ((int)blockIdx.x >> 3);
  int x = l & 63, y = l >> 6;       // 64 row tiles x 12 col tiles
  f32x4 acc[2][2] = {};
  gemm_core_db<64,64>(A, W, K, x*64, y*64, As[0], As[1], Bs[0], Bs[1], acc);
  const int lane = threadIdx.x & 63;
  const int wv   = threadIdx.x >> 6;
  const int wr = wv >> 1, wc = wv & 1;
  const int l4 = lane >> 4, lm = lane & 15;
  const int row0 = x*64, col0 = y*64;
#pragma unroll
  for (int mi=0;mi<2;mi++){
#pragma unroll
    for (int ni=0;ni<2;ni++){
      int col = col0 + wc*32 + ni*16 + lm;
      float bv = bias[col];
#pragma unroll
      for (int j=0;j<4;j++){
        int row = row0 + wr*32 + mi*16 + l4*4 + j;
        C[(size_t)row*N + col] = acc[mi][ni][j] + bv;
      }
    }
  }
}

// ---------------- fused epilogue: bias + RoPE + fragment-pack (q or k), TM=64/TN=128 ----------------
__device__ __forceinline__ void epi_rope(f32x4 (&acc)[2][4], const float* __restrict__ bias,
                                         const int* __restrict__ pos, const float* __restrict__ freqs,
                                         bf16_t* __restrict__ dst, int row0, int col0, float scale){
  const int lane = threadIdx.x & 63;
  const int wv   = threadIdx.x >> 6;
  const int wr = wv >> 1, wc = wv & 1;
  const int l4 = lane >> 4, lm = lane & 15;
  const int par = lm & 1;
#pragma unroll
  for (int ni=0;ni<4;ni++){
    int col = col0 + wc*64 + ni*16 + lm;
    int h = col >> 6, hd = col & 63, f = hd >> 1;
    float F1 = freqs[h*32 + f];
    float F2 = freqs[H_*32 + h*32 + f];
    float bv = bias[col];
    int cc = f >> 3, hi = (f >> 2) & 1;
    int ebase = cc*512 + hi*256 + (f&3)*2 + par;
#pragma unroll
    for (int mi=0;mi<2;mi++){
#pragma unroll
      for (int j=0;j<4;j++){
        int row = row0 + wr*32 + mi*16 + l4*4 + j;
        float v = acc[mi][ni][j] + bv;
        float vp = __shfl_xor(v, 1, 64);
        float p0 = (float)pos[row*2+0], p1 = (float)pos[row*2+1];
        float ang = p0*F1 + p1*F2;
        float sn, cs;
        __sincosf(ang, &sn, &cs);
        float out = (par ? (vp*sn + v*cs) : (v*cs - vp*sn)) * scale;
        int b = row >> 10, s = row & 1023;
        int bh = b*H_ + h, tile = s >> 5, lq = s & 31;
        dst[((size_t)(bh*32 + tile))*2048 + ebase + lq*8] = (bf16_t)out;
      }
    }
  }
}

// ---------------- fused epilogue: bias + V fragment-pack (transpose), TM=64/TN=128 ----------------
__device__ __forceinline__ void epi_vpack(f32x4 (&acc)[2][4], const float* __restrict__ bias,
                                          bf16_t* __restrict__ vfrag, int row0, int col0){
  const int lane = threadIdx.x & 63;
  const int wv   = threadIdx.x >> 6;
  const int wr = wv >> 1, wc = wv & 1;
  const int l4 = lane >> 4, lm = lane & 15;
#pragma unroll
  for (int ni=0;ni<4;ni++){
    int col = col0 + wc*64 + ni*16 + lm;
    int vcol = col - D_;
    int h = vcol >> 6, d = vcol & 63;
    int dt = d >> 5, lq2 = d & 31;
    float bv = bias[col];
    int ebase = dt*1024 + lq2*8;
#pragma unroll
    for (int mi=0;mi<2;mi++){
#pragma unroll
      for (int j=0;j<4;j++){
        int row = row0 + wr*32 + mi*16 + l4*4 + j;
        int b = row >> 10, s = row & 1023;
        int bh = b*H_ + h;
        int kb = s >> 5, ks = (s >> 4) & 1, hi2 = (s >> 3) & 1, jj = s & 7;
        vfrag[((size_t)(bh*32 + kb))*2048 + ebase + ks*512 + hi2*256 + jj]
            = (bf16_t)(acc[mi][ni][j] + bv);
      }
    }
  }
}

// ---------------- fused q-proj + kv-proj + RoPE + pack: 64x128 tiles, dbuf, 1152 blocks ----------------
__global__ void gemm_qkv_kernel(const bf16_t* __restrict__ qn, const bf16_t* __restrict__ kvb,
                                const bf16_t* __restrict__ wq, const bf16_t* __restrict__ wkv,
                                const float* __restrict__ bq, const float* __restrict__ bkv,
                                const int* __restrict__ posq, const int* __restrict__ posk,
                                const float* __restrict__ freqs,
                                bf16_t* __restrict__ qh, bf16_t* __restrict__ kh,
                                bf16_t* __restrict__ vfrag){
  __shared__ bf16_t As[2][64*64];
  __shared__ bf16_t Bs[2][128*64];
  int l = ((int)blockIdx.x & 7)*144 + ((int)blockIdx.x >> 3);
  int x = l & 63, y = l >> 6;       // x: 64 row tiles (64 rows), y: 18 col tiles (128 cols)
  f32x4 acc[2][4] = {};
  if (y < 6){
    gemm_core_db<64,128>(qn, wq, D_, x*64, y*128, As[0], As[1], Bs[0], Bs[1], acc);
    epi_rope(acc, bq, posq, freqs, qh, x*64, y*128, 0.125f*LOG2E);
  } else {
    int c0 = (y-6)*128;
    gemm_core_db<64,128>(kvb, wkv, D_, x*64, c0, As[0], As[1], Bs[0], Bs[1], acc);
    if (y < 12)
      epi_rope(acc, bkv, posk, freqs, kh, x*64, c0, 1.0f);   // K half
    else
      epi_vpack(acc, bkv, vfrag, x*64, c0);                  // V half
  }
}

// ---------------- one attention step: QK^T -> exp2 -> P repack -> PV ----------------
__device__ __forceinline__ void attn_step(const bf16x8 (&kf)[4], const bf16x8 (&vf)[4],
                                          const bf16x8 (&qf)[4], f32x16 (&acc_o)[2],
                                          float &psum){
  f32x16 accs = {};
#pragma unroll
  for (int c=0;c<4;c++)
    accs = __builtin_amdgcn_mfma_f32_32x32x16_bf16(kf[c], qf[c], accs, 0,0,0);
#pragma unroll
  for (int r=0;r<16;r++){
    float v = exp2f(accs[r]);
    accs[r] = v;
    psum += v;
  }
  bf16x8 pa[2];
#pragma unroll
  for (int ks=0;ks<2;ks++){
    const int base = ks*8;
    unsigned int a0 = cvtpk(accs[base+0], accs[base+1]);
    unsigned int a1 = cvtpk(accs[base+2], accs[base+3]);
    unsigned int b0 = cvtpk(accs[base+4], accs[base+5]);
    unsigned int b1 = cvtpk(accs[base+6], accs[base+7]);
    plswap(a0, b0);
    plswap(a1, b1);
    u32x4 w; w[0]=a0; w[1]=a1; w[2]=b0; w[3]=b1;
    pa[ks] = __builtin_bit_cast(bf16x8, w);
  }
#pragma unroll
  for (int dt=0;dt<2;dt++)
#pragma unroll
    for (int ks=0;ks<2;ks++)
      acc_o[dt] = __builtin_amdgcn_mfma_f32_32x32x16_bf16(pa[ks], vf[dt*2+ks], acc_o[dt], 0,0,0);
}

// ---------------- flash attention (R13 kernel, unchanged) ----------------
__global__ __launch_bounds__(256, 3)
void attn_kernel(const bf16_t* __restrict__ Qf, const bf16_t* __restrict__ Kf,
                 const bf16_t* __restrict__ Vf, bf16_t* __restrict__ Oh){
  const int lane = threadIdx.x & 63;
  const int wv   = threadIdx.x >> 6;  // key-quarter 0..3
  const int hi = lane >> 5, lq = lane & 31;
  int l = ((int)blockIdx.x & 7)*192 + ((int)blockIdx.x >> 3);
  const int bh = l >> 5;
  const int qt = l & 31;
  const int q0 = qt*32;
  const int b = bh / H_, h = bh % H_;
  const size_t headoff = ((size_t)b*S_*H_ + h)*HD_;

  __shared__ float part[4][64][33];
  __shared__ float ps[4][32];

  bf16x8 qf[4];
  {
    const bf16_t* qp_ = Qf + (size_t)(bh*32 + qt)*2048 + lane*8;
#pragma unroll
    for (int c=0;c<4;c++)
      qf[c] = *reinterpret_cast<const bf16x8*>(qp_ + c*512);
  }

  const bf16_t* kbase = Kf + ((size_t)bh*32 + wv*8)*2048 + lane*8;
  const bf16_t* vbase = Vf + ((size_t)bh*32 + wv*8)*2048 + lane*8;

  float psum = 0.f;
  f32x16 acc_o[2] = {};

  bf16x8 kfA[4], kfB[4], vf[4];
#pragma unroll
  for (int c=0;c<4;c++)
    kfA[c] = *reinterpret_cast<const bf16x8*>(kbase + c*512);

#pragma unroll
  for (int t=0; t<4; ++t){
    {
      const bf16_t* vp = vbase + (size_t)(2*t)*2048;
#pragma unroll
      for (int j=0;j<4;j++) vf[j] = *reinterpret_cast<const bf16x8*>(vp + j*512);
      const bf16_t* kp = kbase + (size_t)(2*t+1)*2048;
#pragma unroll
      for (int c=0;c<4;c++) kfB[c] = *reinterpret_cast<const bf16x8*>(kp + c*512);
      attn_step(kfA, vf, qf, acc_o, psum);
    }
    {
      const bf16_t* vp = vbase + (size_t)(2*t+1)*2048;
#pragma unroll
      for (int j=0;j<4;j++) vf[j] = *reinterpret_cast<const bf16x8*>(vp + j*512);
      if (t < 3){
        const bf16_t* kp = kbase + (size_t)(2*t+2)*2048;
#pragma unroll
        for (int c=0;c<4;c++) kfA[c] = *reinterpret_cast<const bf16x8*>(kp + c*512);
      }
      attn_step(kfB, vf, qf, acc_o, psum);
    }
  }

  float tp = psum + __shfl_xor(psum, 32, 64);
#pragma unroll
  for (int dt=0;dt<2;dt++)
#pragma unroll
    for (int r=0;r<16;r++)
      part[wv][lane][dt*16+r] = acc_o[dt][r];
  if (lane < 32) ps[wv][lq] = tp;
  __syncthreads();

  const int dt = wv >> 1;
  const int rbase = (wv & 1)*8;
  float tot = ps[0][lq] + ps[1][lq] + ps[2][lq] + ps[3][lq];
  float inv = 1.0f / tot;

  bf16_t* obase = Oh + headoff;
#pragma unroll
  for (int ri=0;ri<8;ri++){
    int r = rbase + ri;
    float s = part[0][lane][dt*16+r] + part[1][lane][dt*16+r]
            + part[2][lane][dt*16+r] + part[3][lane][dt*16+r];
    float invr = __shfl(inv, (r&3) + 8*(r>>2) + 4*hi, 64);
    int qq = q0 + (r&3) + 8*(r>>2) + 4*hi;
    obase[(size_t)qq*RSTRIDE + dt*32 + lq] = (bf16_t)(s*invr);
  }
}

// ---------------- launch ----------------
extern "C" void kernel_launch(void* const* d_in, const int* in_sizes, int n_in,
                              void* d_out, int out_size, void* d_ws, size_t ws_size,
                              hipStream_t stream) {
  const float* q      = (const float*)d_in[0];
  const float* kv     = (const float*)d_in[1];
  const int*   posq   = (const int*)d_in[2];
  const int*   posk   = (const int*)d_in[3];
  const float* w_norm = (const float*)d_in[4];
  const float* w_q    = (const float*)d_in[5];
  const float* b_q    = (const float*)d_in[6];
  const float* w_kv   = (const float*)d_in[7];
  const float* b_kv   = (const float*)d_in[8];
  const float* w_out  = (const float*)d_in[9];
  const float* b_out  = (const float*)d_in[10];
  const float* freqs  = (const float*)d_in[11];
  float* out = (float*)d_out;

  char* p = (char*)d_ws;
  bf16_t* qn   = (bf16_t*)p; p += (size_t)NROW*D_*2;
  bf16_t* kvb  = (bf16_t*)p; p += (size_t)NROW*D_*2;
  bf16_t* wqb  = (bf16_t*)p; p += (size_t)D_*D_*2;
  bf16_t* wkvb = (bf16_t*)p; p += (size_t)2*D_*D_*2;
  bf16_t* wob  = (bf16_t*)p; p += (size_t)D_*D_*2;
  bf16_t* qh   = (bf16_t*)p; p += (size_t)NROW*D_*2;    // Q fragments
  bf16_t* kh   = (bf16_t*)p; p += (size_t)NROW*D_*2;    // K fragments
  bf16_t* vt   = (bf16_t*)p; p += (size_t)NBH*HD_*S_*2; // V fragments
  bf16_t* oh   = (bf16_t*)p; p += (size_t)NROW*D_*2;

  // 1) RMSNorm + all casts
  prep_kernel<<<NROW + 5376, 256, 0, stream>>>(q, w_norm, qn,
                                               w_q, wqb, w_kv, wkvb, w_out, wob, kv, kvb);
  // 2) q-proj + kv-proj GEMM (64x128, double-buffered, prefetch-before-compute)
  gemm_qkv_kernel<<<1152, 256, 0, stream>>>(qn, kvb, wqb, wkvb, b_q, b_kv,
                                            posq, posk, freqs, qh, kh, vt);
  // 3) attention (R13 kernel)
  attn_kernel<<<1536, 256, 0, stream>>>(qh, kh, vt, oh);
  // 4) output projection (64x64, double-buffered) -> f32 d_out
  gemm_kernel<<<768, 256, 0, stream>>>(oh, wob, b_out, out, D_, D_);
}